// Round 1
// baseline (3025.232 us; speedup 1.0000x reference)
//
#include <hip/hip_runtime.h>
#include <cstdio>
#include <cstddef>

#define DH 128

// ---------------------------------------------------------------------------
// Bg[256][128]:  Bg[o][k] = sum_m Wpc[o%128][m] * Wedge[m][(o<128)? k : 128+k]
// so that  g[n][o] = sum_k h[n][k] * Bg[o][k]  gives g1 (o<128) and g2 (o>=128)
// ---------------------------------------------------------------------------
__global__ __launch_bounds__(128) void wc_kernel(const float* __restrict__ Wpc,
                                                 const float* __restrict__ Wedge,
                                                 float* __restrict__ Bg)
{
    int o = blockIdx.x;       // 0..255
    int k = threadIdx.x;      // 0..127
    int orow = o & 127;
    int col  = (o < 128) ? k : (128 + k);
    float acc = 0.f;
    for (int m = 0; m < 128; ++m)
        acc += Wpc[orow * 128 + m] * Wedge[m * 256 + col];
    Bg[o * 128 + k] = acc;
}

// ---------------------------------------------------------------------------
// C[M][OUT] = A[M][128] @ B[OUT][128]^T      (K = 128 fixed)
// 64x64 tile per block, 256 threads, 4x4 register block per thread.
// LDS XOR-swizzled by (row>>2)&7 on float4 granules -> conflict-free reads.
// ---------------------------------------------------------------------------
__global__ __launch_bounds__(256) void gemm_k128(const float* __restrict__ A,
                                                 const float* __restrict__ B,
                                                 float* __restrict__ C,
                                                 int M, int OUT)
{
    __shared__ float As[64][128];
    __shared__ float Bs[64][128];
    const int t    = threadIdx.x;
    const int row0 = blockIdx.x * 64;
    const int out0 = blockIdx.y * 64;

#pragma unroll
    for (int i = 0; i < 8; ++i) {
        int f = i * 256 + t;          // float4 granule id, 0..2047
        int r = f >> 5;               // row in tile
        int g = f & 31;               // granule within row
        int sw = (g ^ ((r >> 2) & 7)) << 2;
        int gr = row0 + r; if (gr > M - 1) gr = M - 1;
        *(float4*)&As[r][sw] = *(const float4*)(A + (size_t)gr * DH + (g << 2));
        *(float4*)&Bs[r][sw] = *(const float4*)(B + (size_t)(out0 + r) * DH + (g << 2));
    }
    __syncthreads();

    const int tx = t & 15, ty = t >> 4;
    const int aswz = ty & 7, bswz = tx & 7;
    float acc[4][4] = {};
#pragma unroll 4
    for (int k4 = 0; k4 < 32; ++k4) {
        float4 a[4], b[4];
#pragma unroll
        for (int i = 0; i < 4; ++i)
            a[i] = *(const float4*)&As[ty * 4 + i][(k4 ^ aswz) << 2];
#pragma unroll
        for (int j = 0; j < 4; ++j)
            b[j] = *(const float4*)&Bs[tx * 4 + j][(k4 ^ bswz) << 2];
#pragma unroll
        for (int i = 0; i < 4; ++i)
#pragma unroll
            for (int j = 0; j < 4; ++j)
                acc[i][j] += a[i].x * b[j].x + a[i].y * b[j].y +
                             a[i].z * b[j].z + a[i].w * b[j].w;
    }

#pragma unroll
    for (int i = 0; i < 4; ++i) {
        int r = row0 + ty * 4 + i;
        if (r < M) {
            float4 v = make_float4(acc[i][0], acc[i][1], acc[i][2], acc[i][3]);
            *(float4*)(C + (size_t)r * OUT + out0 + tx * 4) = v;
        }
    }
}

// ---------------------------------------------------------------------------
// s[n][0] = dot(h[n], wg[0:128]),  s[n][1] = dot(h[n], wg[128:256])
// one wave per row, float2 per lane, wave shuffle reduce
// ---------------------------------------------------------------------------
__global__ __launch_bounds__(256) void s_kernel(const float* __restrict__ h,
                                                const float* __restrict__ wg,
                                                float* __restrict__ s, int Nn)
{
    const int lane = threadIdx.x & 63;
    int wid = (blockIdx.x * blockDim.x + threadIdx.x) >> 6;
    const int nw = (gridDim.x * blockDim.x) >> 6;
    float2 w0 = *(const float2*)(wg + lane * 2);
    float2 w1 = *(const float2*)(wg + 128 + lane * 2);
    for (int n = wid; n < Nn; n += nw) {
        float2 hv = *(const float2*)(h + (size_t)n * DH + lane * 2);
        float p0 = hv.x * w0.x + hv.y * w0.y;
        float p1 = hv.x * w1.x + hv.y * w1.y;
#pragma unroll
        for (int off = 32; off > 0; off >>= 1) {
            p0 += __shfl_down(p0, off);
            p1 += __shfl_down(p1, off);
        }
        if (lane == 0) { s[2 * n] = p0; s[2 * n + 1] = p1; }
    }
}

// ---------------------------------------------------------------------------
// per edge e: alpha = sigmoid(s1[p]+s2[c]+b); v = alpha*(g1[p]+g2[c])
// P[p] += v; P[c] += v       (one wave per edge, float2 per lane)
// ---------------------------------------------------------------------------
__global__ __launch_bounds__(256) void edge_kernel(const int* __restrict__ idx,
                                                   const float* __restrict__ g,
                                                   const float* __restrict__ s,
                                                   const float* __restrict__ gbp,
                                                   float* __restrict__ P,
                                                   int E)
{
    const int lane = threadIdx.x & 63;
    int wid = (blockIdx.x * blockDim.x + threadIdx.x) >> 6;
    const int nw = (gridDim.x * blockDim.x) >> 6;
    const float gb = gbp[0];
    const int j0 = lane << 1;
    for (int e = wid; e < E; e += nw) {
        int p = idx[e];
        int c = idx[E + e];
        float a = 1.f / (1.f + expf(-(s[2 * p] + s[2 * c + 1] + gb)));
        float2 g1 = *(const float2*)(g + (size_t)p * 256 + j0);
        float2 g2 = *(const float2*)(g + (size_t)c * 256 + 128 + j0);
        float vx = a * (g1.x + g2.x);
        float vy = a * (g1.y + g2.y);
        unsafeAtomicAdd(P + (size_t)p * DH + j0,     vx);
        unsafeAtomicAdd(P + (size_t)p * DH + j0 + 1, vy);
        unsafeAtomicAdd(P + (size_t)c * DH + j0,     vx);
        unsafeAtomicAdd(P + (size_t)c * DH + j0 + 1, vy);
    }
}

// ---------------------------------------------------------------------------
// h = h + w * relu(P + h);  P = 0   (w = sigmoid(T - step))
// ---------------------------------------------------------------------------
__global__ __launch_bounds__(256) void post_kernel(float* __restrict__ h,
                                                   float* __restrict__ P,
                                                   const float* __restrict__ Tp,
                                                   float stepf, int n4)
{
    const float w = 1.f / (1.f + expf(-(Tp[0] - stepf)));
    const int stride = gridDim.x * blockDim.x;
    for (int i = blockIdx.x * blockDim.x + threadIdx.x; i < n4; i += stride) {
        float4 hv = ((const float4*)h)[i];
        float4 pv = ((const float4*)P)[i];
        float4 nh;
        nh.x = fmaxf(pv.x + hv.x, 0.f);
        nh.y = fmaxf(pv.y + hv.y, 0.f);
        nh.z = fmaxf(pv.z + hv.z, 0.f);
        nh.w = fmaxf(pv.w + hv.w, 0.f);
        hv.x += w * nh.x;  hv.y += w * nh.y;
        hv.z += w * nh.z;  hv.w += w * nh.w;
        ((float4*)h)[i] = hv;
        ((float4*)P)[i] = make_float4(0.f, 0.f, 0.f, 0.f);
    }
}

// ---------------------------------------------------------------------------
extern "C" void kernel_launch(void* const* d_in, const int* in_sizes, int n_in,
                              void* d_out, int out_size, void* d_ws, size_t ws_size,
                              hipStream_t stream)
{
    const float* x     = (const float*)d_in[0];
    const int*   idx   = (const int*)d_in[1];
    const float* Ws    = (const float*)d_in[2];
    const float* Wpc   = (const float*)d_in[3];
    const float* Wedge = (const float*)d_in[4];
    const float* Wg    = (const float*)d_in[5];
    const float* Wgb   = (const float*)d_in[6];
    const float* Tp    = (const float*)d_in[7];
    const int Nn = in_sizes[0] / DH;     // 100000
    const int E  = in_sizes[1] / 2;      // 500000
    float* h = (float*)d_out;            // hidden state lives in d_out

    const size_t gBytes  = (size_t)Nn * 256 * sizeof(float);
    const size_t pBytes  = (size_t)Nn * DH * sizeof(float);
    const size_t sBytes  = (size_t)Nn * 2 * sizeof(float);
    const size_t bgBytes = 256 * 128 * sizeof(float);
    if (ws_size < gBytes + pBytes + sBytes + bgBytes) {
        fprintf(stderr, "kernel_launch: ws too small (%zu < %zu)\n",
                ws_size, gBytes + pBytes + sBytes + bgBytes);
        return;
    }
    char*  wsb = (char*)d_ws;
    float* g   = (float*)wsb;
    float* P   = (float*)(wsb + gBytes);
    float* s   = (float*)(wsb + gBytes + pBytes);
    float* Bg  = (float*)(wsb + gBytes + pBytes + sBytes);

    hipMemsetAsync(P, 0, pBytes, stream);
    wc_kernel<<<dim3(256), dim3(128), 0, stream>>>(Wpc, Wedge, Bg);
    gemm_k128<<<dim3((Nn + 63) / 64, 2), dim3(256), 0, stream>>>(x, Ws, h, Nn, 128);

    for (int step = 0; step < 3; ++step) {
        gemm_k128<<<dim3((Nn + 63) / 64, 4), dim3(256), 0, stream>>>(h, Bg, g, Nn, 256);
        s_kernel   <<<dim3(2048), dim3(256), 0, stream>>>(h, Wg, s, Nn);
        edge_kernel<<<dim3(2048), dim3(256), 0, stream>>>(idx, g, s, Wgb, P, E);
        post_kernel<<<dim3(2048), dim3(256), 0, stream>>>(h, P, Tp, (float)step,
                                                          Nn * DH / 4);
    }
}

// Round 2
// 1167.660 us; speedup vs baseline: 2.5909x; 2.5909x over previous
//
#include <hip/hip_runtime.h>
#include <cstdio>
#include <cstddef>

#define DH 128

// ---------------------------------------------------------------------------
// Bg[256][128]:  Bg[o][k] = sum_m Wpc[o%128][m] * Wedge[m][(o<128)? k : 128+k]
// so that  g[n][o] = sum_k h[n][k] * Bg[o][k]  gives g1 (o<128) and g2 (o>=128)
// ---------------------------------------------------------------------------
__global__ __launch_bounds__(128) void wc_kernel(const float* __restrict__ Wpc,
                                                 const float* __restrict__ Wedge,
                                                 float* __restrict__ Bg)
{
    int o = blockIdx.x;       // 0..255
    int k = threadIdx.x;      // 0..127
    int orow = o & 127;
    int col  = (o < 128) ? k : (128 + k);
    float acc = 0.f;
    for (int m = 0; m < 128; ++m)
        acc += Wpc[orow * 128 + m] * Wedge[m * 256 + col];
    Bg[o * 128 + k] = acc;
}

// ---------------------------------------------------------------------------
// C[M][OUT] = A[M][128] @ B[OUT][128]^T      (K = 128 fixed)
// 64x64 tile per block, 256 threads, 4x4 register block per thread.
// ---------------------------------------------------------------------------
__global__ __launch_bounds__(256) void gemm_k128(const float* __restrict__ A,
                                                 const float* __restrict__ B,
                                                 float* __restrict__ C,
                                                 int M, int OUT)
{
    __shared__ float As[64][128];
    __shared__ float Bs[64][128];
    const int t    = threadIdx.x;
    const int row0 = blockIdx.x * 64;
    const int out0 = blockIdx.y * 64;

#pragma unroll
    for (int i = 0; i < 8; ++i) {
        int f = i * 256 + t;          // float4 granule id, 0..2047
        int r = f >> 5;               // row in tile
        int g = f & 31;               // granule within row
        int sw = (g ^ ((r >> 2) & 7)) << 2;
        int gr = row0 + r; if (gr > M - 1) gr = M - 1;
        *(float4*)&As[r][sw] = *(const float4*)(A + (size_t)gr * DH + (g << 2));
        *(float4*)&Bs[r][sw] = *(const float4*)(B + (size_t)(out0 + r) * DH + (g << 2));
    }
    __syncthreads();

    const int tx = t & 15, ty = t >> 4;
    const int aswz = ty & 7, bswz = tx & 7;
    float acc[4][4] = {};
#pragma unroll 4
    for (int k4 = 0; k4 < 32; ++k4) {
        float4 a[4], b[4];
#pragma unroll
        for (int i = 0; i < 4; ++i)
            a[i] = *(const float4*)&As[ty * 4 + i][(k4 ^ aswz) << 2];
#pragma unroll
        for (int j = 0; j < 4; ++j)
            b[j] = *(const float4*)&Bs[tx * 4 + j][(k4 ^ bswz) << 2];
#pragma unroll
        for (int i = 0; i < 4; ++i)
#pragma unroll
            for (int j = 0; j < 4; ++j)
                acc[i][j] += a[i].x * b[j].x + a[i].y * b[j].y +
                             a[i].z * b[j].z + a[i].w * b[j].w;
    }

#pragma unroll
    for (int i = 0; i < 4; ++i) {
        int r = row0 + ty * 4 + i;
        if (r < M) {
            float4 v = make_float4(acc[i][0], acc[i][1], acc[i][2], acc[i][3]);
            *(float4*)(C + (size_t)r * OUT + out0 + tx * 4) = v;
        }
    }
}

// ---------------------------------------------------------------------------
// s[n][0] = dot(h[n], wg[0:128]),  s[n][1] = dot(h[n], wg[128:256])
// ---------------------------------------------------------------------------
__global__ __launch_bounds__(256) void s_kernel(const float* __restrict__ h,
                                                const float* __restrict__ wg,
                                                float* __restrict__ s, int Nn)
{
    const int lane = threadIdx.x & 63;
    int wid = (blockIdx.x * blockDim.x + threadIdx.x) >> 6;
    const int nw = (gridDim.x * blockDim.x) >> 6;
    float2 w0 = *(const float2*)(wg + lane * 2);
    float2 w1 = *(const float2*)(wg + 128 + lane * 2);
    for (int n = wid; n < Nn; n += nw) {
        float2 hv = *(const float2*)(h + (size_t)n * DH + lane * 2);
        float p0 = hv.x * w0.x + hv.y * w0.y;
        float p1 = hv.x * w1.x + hv.y * w1.y;
#pragma unroll
        for (int off = 32; off > 0; off >>= 1) {
            p0 += __shfl_down(p0, off);
            p1 += __shfl_down(p1, off);
        }
        if (lane == 0) { s[2 * n] = p0; s[2 * n + 1] = p1; }
    }
}

// ===========================================================================
// CSR build (once per call)
// ===========================================================================
__global__ __launch_bounds__(256) void count_k(const int* __restrict__ idx,
                                               int* __restrict__ cnt, int twoE)
{
    const int stride = gridDim.x * blockDim.x;
    for (int i = blockIdx.x * blockDim.x + threadIdx.x; i < twoE; i += stride)
        atomicAdd(cnt + idx[i], 1);
}

#define SCAN_B 256
__global__ __launch_bounds__(SCAN_B) void scan1(const int* __restrict__ cnt,
                                                int* __restrict__ bsum, int Nn)
{
    __shared__ int sm[SCAN_B];
    int i = blockIdx.x * SCAN_B + threadIdx.x;
    sm[threadIdx.x] = (i < Nn) ? cnt[i] : 0;
    __syncthreads();
    for (int off = SCAN_B / 2; off > 0; off >>= 1) {
        if (threadIdx.x < off) sm[threadIdx.x] += sm[threadIdx.x + off];
        __syncthreads();
    }
    if (threadIdx.x == 0) bsum[blockIdx.x] = sm[0];
}

__global__ __launch_bounds__(1024) void scan2(int* __restrict__ bsum, int nb,
                                              int* __restrict__ totalOut)
{
    __shared__ int sm[1024];
    int t = threadIdx.x;
    sm[t] = (t < nb) ? bsum[t] : 0;
    __syncthreads();
    for (int off = 1; off < 1024; off <<= 1) {
        int u = (t >= off) ? sm[t - off] : 0;
        __syncthreads();
        sm[t] += u;
        __syncthreads();
    }
    if (t < nb) bsum[t] = (t == 0) ? 0 : sm[t - 1];  // exclusive block offsets
    if (t == nb - 1) *totalOut = sm[t];              // base[Nn] = total (2E)
}

__global__ __launch_bounds__(SCAN_B) void scan3(const int* __restrict__ cnt,
                                                const int* __restrict__ bsum,
                                                int* __restrict__ base, int Nn)
{
    __shared__ int sm[SCAN_B];
    int i = blockIdx.x * SCAN_B + threadIdx.x;
    int v = (i < Nn) ? cnt[i] : 0;
    sm[threadIdx.x] = v;
    __syncthreads();
    for (int off = 1; off < SCAN_B; off <<= 1) {
        int u = (threadIdx.x >= off) ? sm[threadIdx.x - off] : 0;
        __syncthreads();
        sm[threadIdx.x] += u;
        __syncthreads();
    }
    if (i < Nn) base[i] = bsum[blockIdx.x] + sm[threadIdx.x] - v;  // exclusive
}

__global__ __launch_bounds__(256) void fill_k(const int* __restrict__ idx,
                                              int* __restrict__ cursor,
                                              int* __restrict__ adj, int E)
{
    const int stride = gridDim.x * blockDim.x;
    const int twoE = 2 * E;
    for (int i = blockIdx.x * blockDim.x + threadIdx.x; i < twoE; i += stride) {
        int node = idx[i];
        int e = (i < E) ? i : i - E;
        int pos = atomicAdd(cursor + node, 1);
        adj[pos] = e;
    }
}

__global__ __launch_bounds__(256) void pc_k(const int* __restrict__ idx,
                                            int2* __restrict__ pc, int E)
{
    const int stride = gridDim.x * blockDim.x;
    for (int e = blockIdx.x * blockDim.x + threadIdx.x; e < E; e += stride)
        pc[e] = make_int2(idx[e], idx[E + e]);
}

// ===========================================================================
// per-step kernels
// ===========================================================================
__global__ __launch_bounds__(256) void alpha_k(const int2* __restrict__ pc,
                                               const float* __restrict__ s,
                                               const float* __restrict__ gbp,
                                               float* __restrict__ alpha, int E)
{
    const float gb = gbp[0];
    const int stride = gridDim.x * blockDim.x;
    for (int e = blockIdx.x * blockDim.x + threadIdx.x; e < E; e += stride) {
        int2 q = pc[e];
        alpha[e] = 1.f / (1.f + expf(-(s[2 * q.x] + s[2 * q.y + 1] + gb)));
    }
}

// one wave per node: acc = sum_{e in inc(n)} alpha[e]*(g1[p_e]+g2[c_e])
// then h = h + w*relu(acc + h)
__global__ __launch_bounds__(256) void agg_kernel(const float* __restrict__ g,
                                                  const float* __restrict__ alpha,
                                                  const int2* __restrict__ pc,
                                                  const int* __restrict__ base,
                                                  const int* __restrict__ adj,
                                                  float* __restrict__ h,
                                                  const float* __restrict__ Tp,
                                                  float stepf, int Nn)
{
    const int lane = threadIdx.x & 63;
    const int n = (blockIdx.x * blockDim.x + threadIdx.x) >> 6;
    if (n >= Nn) return;
    const float w = 1.f / (1.f + expf(-(Tp[0] - stepf)));
    const int b0 = base[n], b1 = base[n + 1];
    const int j0 = lane << 1;
    float ax = 0.f, ay = 0.f;
    for (int i = b0; i < b1; ++i) {
        int e = adj[i];
        float a = alpha[e];
        int2 q = pc[e];
        float2 g1 = *(const float2*)(g + (size_t)q.x * 256 + j0);
        float2 g2 = *(const float2*)(g + (size_t)q.y * 256 + 128 + j0);
        ax += a * (g1.x + g2.x);
        ay += a * (g1.y + g2.y);
    }
    float2 hv = *(const float2*)(h + (size_t)n * DH + j0);
    float nx = fmaxf(ax + hv.x, 0.f);
    float ny = fmaxf(ay + hv.y, 0.f);
    hv.x += w * nx;
    hv.y += w * ny;
    *(float2*)(h + (size_t)n * DH + j0) = hv;
}

// ---------------------------------------------------------------------------
static inline size_t alignUp(size_t x) { return (x + 255) & ~(size_t)255; }

extern "C" void kernel_launch(void* const* d_in, const int* in_sizes, int n_in,
                              void* d_out, int out_size, void* d_ws, size_t ws_size,
                              hipStream_t stream)
{
    const float* x     = (const float*)d_in[0];
    const int*   idx   = (const int*)d_in[1];
    const float* Ws    = (const float*)d_in[2];
    const float* Wpc   = (const float*)d_in[3];
    const float* Wedge = (const float*)d_in[4];
    const float* Wg    = (const float*)d_in[5];
    const float* Wgb   = (const float*)d_in[6];
    const float* Tp    = (const float*)d_in[7];
    const int Nn = in_sizes[0] / DH;     // 100000
    const int E  = in_sizes[1] / 2;      // 500000
    float* h = (float*)d_out;            // hidden state lives in d_out

    const int nb = (Nn + SCAN_B - 1) / SCAN_B;   // scan blocks (391)
    if (nb > 1024) { fprintf(stderr, "kernel_launch: Nn too big for scan\n"); return; }

    // workspace carve-up
    size_t off = 0;
    char* wsb = (char*)d_ws;
    float* g     = (float*)(wsb + off); off = alignUp(off + (size_t)Nn * 256 * 4);
    float* s     = (float*)(wsb + off); off = alignUp(off + (size_t)Nn * 2 * 4);
    float* Bg    = (float*)(wsb + off); off = alignUp(off + 256 * 128 * 4);
    float* alpha = (float*)(wsb + off); off = alignUp(off + (size_t)E * 4);
    int2*  pc    = (int2*) (wsb + off); off = alignUp(off + (size_t)E * 8);
    int*   cnt   = (int*)  (wsb + off); off = alignUp(off + (size_t)Nn * 4);
    int*   base  = (int*)  (wsb + off); off = alignUp(off + (size_t)(Nn + 1) * 4);
    int*   bsum  = (int*)  (wsb + off); off = alignUp(off + 1024 * 4);
    int*   adj   = (int*)  (wsb + off); off = alignUp(off + (size_t)(2 * E) * 4);
    if (off > ws_size) {
        fprintf(stderr, "kernel_launch: ws too small (%zu < %zu)\n", ws_size, off);
        return;
    }

    // ---- CSR build (deterministic per call) ----
    hipMemsetAsync(cnt, 0, (size_t)Nn * 4, stream);
    count_k<<<dim3(2048), dim3(256), 0, stream>>>(idx, cnt, 2 * E);
    scan1<<<dim3(nb), dim3(SCAN_B), 0, stream>>>(cnt, bsum, Nn);
    scan2<<<dim3(1), dim3(1024), 0, stream>>>(bsum, nb, base + Nn);
    scan3<<<dim3(nb), dim3(SCAN_B), 0, stream>>>(cnt, bsum, base, Nn);
    hipMemcpyAsync(cnt, base, (size_t)Nn * 4, hipMemcpyDeviceToDevice, stream); // cursor
    fill_k<<<dim3(2048), dim3(256), 0, stream>>>(idx, cnt, adj, E);
    pc_k<<<dim3(512), dim3(256), 0, stream>>>(idx, pc, E);

    // ---- weights + init ----
    wc_kernel<<<dim3(256), dim3(128), 0, stream>>>(Wpc, Wedge, Bg);
    gemm_k128<<<dim3((Nn + 63) / 64, 2), dim3(256), 0, stream>>>(x, Ws, h, Nn, 128);

    // ---- 3 steps ----
    const int aggBlocks = (Nn * 64 + 255) / 256;
    for (int step = 0; step < 3; ++step) {
        gemm_k128<<<dim3((Nn + 63) / 64, 4), dim3(256), 0, stream>>>(h, Bg, g, Nn, 256);
        s_kernel<<<dim3(1024), dim3(256), 0, stream>>>(h, Wg, s, Nn);
        alpha_k<<<dim3(1024), dim3(256), 0, stream>>>(pc, s, Wgb, alpha, E);
        agg_kernel<<<dim3(aggBlocks), dim3(256), 0, stream>>>(g, alpha, pc, base, adj,
                                                              h, Tp, (float)step, Nn);
    }
}

// Round 3
// 778.398 us; speedup vs baseline: 3.8865x; 1.5001x over previous
//
#include <hip/hip_runtime.h>
#include <cstdio>
#include <cstddef>

#define DH 128

typedef _Float16 f16;
typedef __attribute__((ext_vector_type(8))) _Float16 f16x8;
typedef __attribute__((ext_vector_type(2))) _Float16 f16x2;
typedef __attribute__((ext_vector_type(4))) float    f32x4;

// ---------------------------------------------------------------------------
// Bg16[256][128]: Bg[o][k] = sum_m Wpc[o&127][m] * Wedge[m][(o<128)? k : 128+k]
// ---------------------------------------------------------------------------
__global__ __launch_bounds__(128) void wc_kernel(const float* __restrict__ Wpc,
                                                 const float* __restrict__ Wedge,
                                                 f16* __restrict__ Bg16)
{
    int o = blockIdx.x;       // 0..255
    int k = threadIdx.x;      // 0..127
    int orow = o & 127;
    int col  = (o < 128) ? k : (128 + k);
    float acc = 0.f;
    for (int m = 0; m < 128; ++m)
        acc += Wpc[orow * 128 + m] * Wedge[m * 256 + col];
    Bg16[o * 128 + k] = (f16)acc;
}

// ---------------------------------------------------------------------------
__global__ __launch_bounds__(256) void cast_k(const float* __restrict__ src,
                                              f16* __restrict__ dst, int n4)
{
    const int stride = gridDim.x * blockDim.x;
    for (int i = blockIdx.x * blockDim.x + threadIdx.x; i < n4; i += stride) {
        float4 v = ((const float4*)src)[i];
        f16x2 a = {(f16)v.x, (f16)v.y};
        f16x2 b = {(f16)v.z, (f16)v.w};
        ((f16x2*)dst)[2 * i]     = a;
        ((f16x2*)dst)[2 * i + 1] = b;
    }
}

// ---------------------------------------------------------------------------
// C[M][OUT] = A16[M][128] @ B16[OUT][128]^T via mfma_f32_16x16x32_f16.
// One wave -> 16 rows x OUT cols. A frags held in regs; B frags from L2.
// Optionally writes f32 C (Cf) and/or f16 C (Ch).
// ---------------------------------------------------------------------------
__global__ __launch_bounds__(256) void mfma_gemm(const f16* __restrict__ A16,
                                                 const f16* __restrict__ B16,
                                                 float* __restrict__ Cf,
                                                 f16* __restrict__ Ch,
                                                 int M, int OUT)
{
    const int wave = threadIdx.x >> 6, lane = threadIdx.x & 63;
    const int row0 = blockIdx.x * 64 + wave * 16;
    const int r  = lane & 15;
    const int kg = lane >> 4;              // k-group 0..3 (8 halves each)

    int arow = row0 + r; if (arow > M - 1) arow = M - 1;
    const f16x8* Ap = (const f16x8*)(A16 + (size_t)arow * 128 + kg * 8);
    f16x8 a0 = Ap[0], a1 = Ap[4], a2 = Ap[8], a3 = Ap[12];   // k-steps of 32

    const int nct = OUT >> 4;
    for (int ct = 0; ct < nct; ++ct) {
        const f16x8* Bp = (const f16x8*)(B16 + (size_t)(ct * 16 + r) * 128 + kg * 8);
        f32x4 acc = {0.f, 0.f, 0.f, 0.f};
        acc = __builtin_amdgcn_mfma_f32_16x16x32_f16(a0, Bp[0],  acc, 0, 0, 0);
        acc = __builtin_amdgcn_mfma_f32_16x16x32_f16(a1, Bp[4],  acc, 0, 0, 0);
        acc = __builtin_amdgcn_mfma_f32_16x16x32_f16(a2, Bp[8],  acc, 0, 0, 0);
        acc = __builtin_amdgcn_mfma_f32_16x16x32_f16(a3, Bp[12], acc, 0, 0, 0);
        const int ccol  = ct * 16 + r;                // C: col = lane&15
        const int crow0 = row0 + (lane >> 4) * 4;     //    row = (lane>>4)*4 + j
#pragma unroll
        for (int j = 0; j < 4; ++j) {
            int cr = crow0 + j;
            if (cr < M) {
                if (Cf) Cf[(size_t)cr * OUT + ccol] = acc[j];
                if (Ch) Ch[(size_t)cr * OUT + ccol] = (f16)acc[j];
            }
        }
    }
}

// ---------------------------------------------------------------------------
// s[n][0] = dot(h[n], wg[0:128]),  s[n][1] = dot(h[n], wg[128:256])
// (used once after init; later steps produce s inside agg)
// ---------------------------------------------------------------------------
__global__ __launch_bounds__(256) void s_kernel(const float* __restrict__ h,
                                                const float* __restrict__ wg,
                                                float* __restrict__ s, int Nn)
{
    const int lane = threadIdx.x & 63;
    int wid = (blockIdx.x * blockDim.x + threadIdx.x) >> 6;
    const int nw = (gridDim.x * blockDim.x) >> 6;
    float2 w0 = *(const float2*)(wg + lane * 2);
    float2 w1 = *(const float2*)(wg + 128 + lane * 2);
    for (int n = wid; n < Nn; n += nw) {
        float2 hv = *(const float2*)(h + (size_t)n * DH + lane * 2);
        float p0 = hv.x * w0.x + hv.y * w0.y;
        float p1 = hv.x * w1.x + hv.y * w1.y;
#pragma unroll
        for (int off = 32; off > 0; off >>= 1) {
            p0 += __shfl_down(p0, off);
            p1 += __shfl_down(p1, off);
        }
        if (lane == 0) { s[2 * n] = p0; s[2 * n + 1] = p1; }
    }
}

// ===========================================================================
// CSR build (once per call)
// ===========================================================================
__global__ __launch_bounds__(256) void count_k(const int* __restrict__ idx,
                                               int* __restrict__ cnt, int twoE)
{
    const int stride = gridDim.x * blockDim.x;
    for (int i = blockIdx.x * blockDim.x + threadIdx.x; i < twoE; i += stride)
        atomicAdd(cnt + idx[i], 1);
}

#define SCAN_B 256
__global__ __launch_bounds__(SCAN_B) void scan1(const int* __restrict__ cnt,
                                                int* __restrict__ bsum, int Nn)
{
    __shared__ int sm[SCAN_B];
    int i = blockIdx.x * SCAN_B + threadIdx.x;
    sm[threadIdx.x] = (i < Nn) ? cnt[i] : 0;
    __syncthreads();
    for (int off = SCAN_B / 2; off > 0; off >>= 1) {
        if (threadIdx.x < off) sm[threadIdx.x] += sm[threadIdx.x + off];
        __syncthreads();
    }
    if (threadIdx.x == 0) bsum[blockIdx.x] = sm[0];
}

__global__ __launch_bounds__(1024) void scan2(int* __restrict__ bsum, int nb,
                                              int* __restrict__ totalOut)
{
    __shared__ int sm[1024];
    int t = threadIdx.x;
    sm[t] = (t < nb) ? bsum[t] : 0;
    __syncthreads();
    for (int off = 1; off < 1024; off <<= 1) {
        int u = (t >= off) ? sm[t - off] : 0;
        __syncthreads();
        sm[t] += u;
        __syncthreads();
    }
    if (t < nb) bsum[t] = (t == 0) ? 0 : sm[t - 1];
    if (t == nb - 1) *totalOut = sm[t];
}

__global__ __launch_bounds__(SCAN_B) void scan3(const int* __restrict__ cnt,
                                                const int* __restrict__ bsum,
                                                int* __restrict__ base, int Nn)
{
    __shared__ int sm[SCAN_B];
    int i = blockIdx.x * SCAN_B + threadIdx.x;
    int v = (i < Nn) ? cnt[i] : 0;
    sm[threadIdx.x] = v;
    __syncthreads();
    for (int off = 1; off < SCAN_B; off <<= 1) {
        int u = (threadIdx.x >= off) ? sm[threadIdx.x - off] : 0;
        __syncthreads();
        sm[threadIdx.x] += u;
        __syncthreads();
    }
    if (i < Nn) base[i] = bsum[blockIdx.x] + sm[threadIdx.x] - v;
}

// adj2[pos] = { e | side<<30, other }   side: 0 = node is parent, 1 = child
__global__ __launch_bounds__(256) void fill_k(const int* __restrict__ idx,
                                              int* __restrict__ cursor,
                                              int2* __restrict__ adj2, int E)
{
    const int stride = gridDim.x * blockDim.x;
    const int twoE = 2 * E;
    for (int i = blockIdx.x * blockDim.x + threadIdx.x; i < twoE; i += stride) {
        int side = (i >= E);
        int e    = side ? i - E : i;
        int node  = idx[i];
        int other = side ? idx[e] : idx[E + e];
        int pos = atomicAdd(cursor + node, 1);
        adj2[pos] = make_int2(e | (side << 30), other);
    }
}

__global__ __launch_bounds__(256) void pc_k(const int* __restrict__ idx,
                                            int2* __restrict__ pc, int E)
{
    const int stride = gridDim.x * blockDim.x;
    for (int e = blockIdx.x * blockDim.x + threadIdx.x; e < E; e += stride)
        pc[e] = make_int2(idx[e], idx[E + e]);
}

// ===========================================================================
// per-step kernels
// ===========================================================================
__global__ __launch_bounds__(256) void alpha_k(const int2* __restrict__ pc,
                                               const float* __restrict__ s,
                                               const float* __restrict__ gbp,
                                               float* __restrict__ alpha, int E)
{
    const float gb = gbp[0];
    const int stride = gridDim.x * blockDim.x;
    for (int e = blockIdx.x * blockDim.x + threadIdx.x; e < E; e += stride) {
        int2 q = pc[e];
        alpha[e] = 1.f / (1.f + expf(-(s[2 * q.x] + s[2 * q.y + 1] + gb)));
    }
}

// one wave per node:
//   acc = aP*g1[n] + aC*g2[n] + sum_e alpha[e]*(other endpoint's half)
//   h = h + w*relu(acc + h);  h16 = (f16)h;  s_next = h . wg halves
__global__ __launch_bounds__(256) void agg2(const f16* __restrict__ g16,
                                            const float* __restrict__ alpha,
                                            const int2* __restrict__ adj2,
                                            const int* __restrict__ base,
                                            float* __restrict__ h,
                                            f16* __restrict__ h16,
                                            float* __restrict__ s,
                                            const float* __restrict__ wg,
                                            const float* __restrict__ Tp,
                                            float stepf, int Nn)
{
    const int lane = threadIdx.x & 63;
    const int n = (blockIdx.x * blockDim.x + threadIdx.x) >> 6;
    if (n >= Nn) return;
    const float w = 1.f / (1.f + expf(-(Tp[0] - stepf)));
    const int b0 = base[n], b1 = base[n + 1];
    const int j0 = lane << 1;
    float ax = 0.f, ay = 0.f, aP = 0.f, aC = 0.f;
    for (int i = b0; i < b1; ++i) {
        int2 ad = adj2[i];
        int e    = ad.x & 0x3FFFFFFF;
        int side = ad.x >> 30;           // 0: n parent -> gather other's g2
        float a  = alpha[e];
        size_t goff = (size_t)ad.y * 256 + ((side ^ 1) << 7) + j0;
        f16x2 gv = *(const f16x2*)(g16 + goff);
        if (side == 0) aP += a; else aC += a;
        ax += a * (float)gv.x;
        ay += a * (float)gv.y;
    }
    f16x2 o1 = *(const f16x2*)(g16 + (size_t)n * 256 + j0);
    f16x2 o2 = *(const f16x2*)(g16 + (size_t)n * 256 + 128 + j0);
    ax += aP * (float)o1.x + aC * (float)o2.x;
    ay += aP * (float)o1.y + aC * (float)o2.y;

    float2 hv = *(const float2*)(h + (size_t)n * DH + j0);
    hv.x += w * fmaxf(ax + hv.x, 0.f);
    hv.y += w * fmaxf(ay + hv.y, 0.f);
    *(float2*)(h + (size_t)n * DH + j0) = hv;
    f16x2 h2v = {(f16)hv.x, (f16)hv.y};
    *(f16x2*)(h16 + (size_t)n * DH + j0) = h2v;

    // fused s for next step
    float2 w0 = *(const float2*)(wg + j0);
    float2 w1 = *(const float2*)(wg + 128 + j0);
    float p0 = hv.x * w0.x + hv.y * w0.y;
    float p1 = hv.x * w1.x + hv.y * w1.y;
#pragma unroll
    for (int off = 32; off > 0; off >>= 1) {
        p0 += __shfl_down(p0, off);
        p1 += __shfl_down(p1, off);
    }
    if (lane == 0) { s[2 * n] = p0; s[2 * n + 1] = p1; }
}

// ---------------------------------------------------------------------------
static inline size_t alignUp(size_t x) { return (x + 255) & ~(size_t)255; }

extern "C" void kernel_launch(void* const* d_in, const int* in_sizes, int n_in,
                              void* d_out, int out_size, void* d_ws, size_t ws_size,
                              hipStream_t stream)
{
    const float* x     = (const float*)d_in[0];
    const int*   idx   = (const int*)d_in[1];
    const float* Ws    = (const float*)d_in[2];
    const float* Wpc   = (const float*)d_in[3];
    const float* Wedge = (const float*)d_in[4];
    const float* Wg    = (const float*)d_in[5];
    const float* Wgb   = (const float*)d_in[6];
    const float* Tp    = (const float*)d_in[7];
    const int Nn = in_sizes[0] / DH;     // 100000
    const int E  = in_sizes[1] / 2;      // 500000
    float* h = (float*)d_out;

    const int nb = (Nn + SCAN_B - 1) / SCAN_B;
    if (nb > 1024) { fprintf(stderr, "kernel_launch: Nn too big for scan\n"); return; }

    // workspace carve-up
    size_t off = 0;
    char* wsb = (char*)d_ws;
    f16*   g16   = (f16*)  (wsb + off); off = alignUp(off + (size_t)Nn * 256 * 2);
    f16*   h16   = (f16*)  (wsb + off); off = alignUp(off + (size_t)Nn * DH * 2);
    f16*   x16   = (f16*)  (wsb + off); off = alignUp(off + (size_t)Nn * DH * 2);
    f16*   Ws16  = (f16*)  (wsb + off); off = alignUp(off + 128 * 128 * 2);
    f16*   Bg16  = (f16*)  (wsb + off); off = alignUp(off + 256 * 128 * 2);
    float* s     = (float*)(wsb + off); off = alignUp(off + (size_t)Nn * 2 * 4);
    float* alpha = (float*)(wsb + off); off = alignUp(off + (size_t)E * 4);
    int2*  pc    = (int2*) (wsb + off); off = alignUp(off + (size_t)E * 8);
    int*   cnt   = (int*)  (wsb + off); off = alignUp(off + (size_t)Nn * 4);
    int*   base  = (int*)  (wsb + off); off = alignUp(off + (size_t)(Nn + 1) * 4);
    int*   bsum  = (int*)  (wsb + off); off = alignUp(off + 1024 * 4);
    int2*  adj2  = (int2*) (wsb + off); off = alignUp(off + (size_t)(2 * E) * 8);
    if (off > ws_size) {
        fprintf(stderr, "kernel_launch: ws too small (%zu < %zu)\n", ws_size, off);
        return;
    }

    // ---- CSR build ----
    hipMemsetAsync(cnt, 0, (size_t)Nn * 4, stream);
    count_k<<<dim3(2048), dim3(256), 0, stream>>>(idx, cnt, 2 * E);
    scan1<<<dim3(nb), dim3(SCAN_B), 0, stream>>>(cnt, bsum, Nn);
    scan2<<<dim3(1), dim3(1024), 0, stream>>>(bsum, nb, base + Nn);
    scan3<<<dim3(nb), dim3(SCAN_B), 0, stream>>>(cnt, bsum, base, Nn);
    hipMemcpyAsync(cnt, base, (size_t)Nn * 4, hipMemcpyDeviceToDevice, stream);
    fill_k<<<dim3(2048), dim3(256), 0, stream>>>(idx, cnt, adj2, E);
    pc_k<<<dim3(512), dim3(256), 0, stream>>>(idx, pc, E);

    // ---- weights + init ----
    wc_kernel<<<dim3(256), dim3(128), 0, stream>>>(Wpc, Wedge, Bg16);
    cast_k<<<dim3(64), dim3(256), 0, stream>>>(Ws, Ws16, 128 * 128 / 4);
    cast_k<<<dim3(2048), dim3(256), 0, stream>>>(x, x16, Nn * DH / 4);
    mfma_gemm<<<dim3((Nn + 63) / 64), dim3(256), 0, stream>>>(x16, Ws16, h, h16, Nn, 128);
    s_kernel<<<dim3(1024), dim3(256), 0, stream>>>(h, Wg, s, Nn);

    // ---- 3 steps ----
    const int aggBlocks = (Nn * 64 + 255) / 256;
    for (int step = 0; step < 3; ++step) {
        mfma_gemm<<<dim3((Nn + 63) / 64), dim3(256), 0, stream>>>(h16, Bg16, nullptr, g16, Nn, 256);
        alpha_k<<<dim3(1024), dim3(256), 0, stream>>>(pc, s, Wgb, alpha, E);
        agg2<<<dim3(aggBlocks), dim3(256), 0, stream>>>(g16, alpha, adj2, base, h, h16,
                                                        s, Wg, Tp, (float)step, Nn);
    }
}

// Round 4
// 576.831 us; speedup vs baseline: 5.2446x; 1.3494x over previous
//
#include <hip/hip_runtime.h>
#include <cstdio>
#include <cstddef>

#define DH 128

typedef _Float16 f16;
typedef __attribute__((ext_vector_type(8))) _Float16 f16x8;
typedef __attribute__((ext_vector_type(2))) _Float16 f16x2;
typedef __attribute__((ext_vector_type(4))) float    f32x4;

// ---------------------------------------------------------------------------
// blocks 0..255:  Bg16[o][k] = sum_m Wpc[o&127][m] * Wedge[m][(o<128)? k:128+k]
// blocks 256..383: Ws16 cast
// ---------------------------------------------------------------------------
__global__ __launch_bounds__(128) void wc_kernel(const float* __restrict__ Wpc,
                                                 const float* __restrict__ Wedge,
                                                 const float* __restrict__ Ws,
                                                 f16* __restrict__ Bg16,
                                                 f16* __restrict__ Ws16)
{
    int o = blockIdx.x;
    int k = threadIdx.x;
    if (o < 256) {
        int orow = o & 127;
        int col  = (o < 128) ? k : (128 + k);
        float acc = 0.f;
        for (int m = 0; m < 128; ++m)
            acc += Wpc[orow * 128 + m] * Wedge[m * 256 + col];
        Bg16[o * 128 + k] = (f16)acc;
    } else {
        int row = o - 256;
        Ws16[row * 128 + k] = (f16)Ws[row * 128 + k];
    }
}

// ---------------------------------------------------------------------------
// prep: degree count (atomics) + x -> x16 cast, one grid-stride kernel
// ---------------------------------------------------------------------------
__global__ __launch_bounds__(256) void prep_k(const int* __restrict__ idx,
                                              int* __restrict__ cnt, int twoE,
                                              const float* __restrict__ x,
                                              f16* __restrict__ x16, int n4)
{
    const int stride = gridDim.x * blockDim.x;
    const int mx = (twoE > n4) ? twoE : n4;
    for (int i = blockIdx.x * blockDim.x + threadIdx.x; i < mx; i += stride) {
        if (i < twoE) atomicAdd(cnt + idx[i], 1);
        if (i < n4) {
            float4 v = ((const float4*)x)[i];
            f16x2 a = {(f16)v.x, (f16)v.y};
            f16x2 b = {(f16)v.z, (f16)v.w};
            ((f16x2*)x16)[2 * i]     = a;
            ((f16x2*)x16)[2 * i + 1] = b;
        }
    }
}

// ---------------------------------------------------------------------------
// C[M][OUT] = A16[M][128] @ B16[OUT][128]^T via mfma_f32_16x16x32_f16.
// One wave -> 16 rows x OUT cols. Optional fused s = h . wg halves (init path).
// ---------------------------------------------------------------------------
template<int OUT, bool WF32, bool WF16, bool FUSES>
__global__ __launch_bounds__(256) void mfma_gemm_t(const f16* __restrict__ A16,
                                                   const f16* __restrict__ B16,
                                                   float* __restrict__ Cf,
                                                   f16* __restrict__ Ch,
                                                   const float* __restrict__ wg,
                                                   float* __restrict__ s,
                                                   int M)
{
    const int lane = threadIdx.x & 63;
    const int row0 = blockIdx.x * 64 + (threadIdx.x >> 6) * 16;
    const int r = lane & 15, kg = lane >> 4;

    int arow = row0 + r; if (arow > M - 1) arow = M - 1;
    const f16x8* Ap = (const f16x8*)(A16 + (size_t)arow * 128 + kg * 8);
    f16x8 a0 = Ap[0], a1 = Ap[4], a2 = Ap[8], a3 = Ap[12];

    float sp0[4], sp1[4];
    if constexpr (FUSES) {
#pragma unroll
        for (int j = 0; j < 4; ++j) { sp0[j] = 0.f; sp1[j] = 0.f; }
    }

    const int crow0 = row0 + kg * 4;
#pragma unroll 2
    for (int ct = 0; ct < OUT / 16; ++ct) {
        const f16x8* Bp = (const f16x8*)(B16 + (size_t)(ct * 16 + r) * 128 + kg * 8);
        f16x8 b0 = Bp[0], b1 = Bp[4], b2 = Bp[8], b3 = Bp[12];
        f32x4 acc0 = {0.f, 0.f, 0.f, 0.f}, acc1 = {0.f, 0.f, 0.f, 0.f};
        acc0 = __builtin_amdgcn_mfma_f32_16x16x32_f16(a0, b0, acc0, 0, 0, 0);
        acc1 = __builtin_amdgcn_mfma_f32_16x16x32_f16(a2, b2, acc1, 0, 0, 0);
        acc0 = __builtin_amdgcn_mfma_f32_16x16x32_f16(a1, b1, acc0, 0, 0, 0);
        acc1 = __builtin_amdgcn_mfma_f32_16x16x32_f16(a3, b3, acc1, 0, 0, 0);
        const int ccol = ct * 16 + r;
        float wg0 = 0.f, wg1 = 0.f;
        if constexpr (FUSES) { wg0 = wg[ccol]; wg1 = wg[128 + ccol]; }
#pragma unroll
        for (int j = 0; j < 4; ++j) {
            float v = acc0[j] + acc1[j];
            int cr = crow0 + j;
            if (cr < M) {
                if constexpr (WF32) Cf[(size_t)cr * OUT + ccol] = v;
                if constexpr (WF16) Ch[(size_t)cr * OUT + ccol] = (f16)v;
            }
            if constexpr (FUSES) { sp0[j] += v * wg0; sp1[j] += v * wg1; }
        }
    }
    if constexpr (FUSES) {
#pragma unroll
        for (int j = 0; j < 4; ++j) {
            float p0 = sp0[j], p1 = sp1[j];
#pragma unroll
            for (int off = 1; off <= 8; off <<= 1) {
                p0 += __shfl_xor(p0, off);
                p1 += __shfl_xor(p1, off);
            }
            if (r == 0) {
                int row = crow0 + j;
                if (row < M) { s[2 * row] = p0; s[2 * row + 1] = p1; }
            }
        }
    }
}

// ===========================================================================
// CSR build (once per call)
// ===========================================================================
#define SCAN_B 256
__global__ __launch_bounds__(SCAN_B) void scan1(const int* __restrict__ cnt,
                                                int* __restrict__ bsum, int Nn)
{
    __shared__ int sm[SCAN_B];
    int i = blockIdx.x * SCAN_B + threadIdx.x;
    sm[threadIdx.x] = (i < Nn) ? cnt[i] : 0;
    __syncthreads();
    for (int off = SCAN_B / 2; off > 0; off >>= 1) {
        if (threadIdx.x < off) sm[threadIdx.x] += sm[threadIdx.x + off];
        __syncthreads();
    }
    if (threadIdx.x == 0) bsum[blockIdx.x] = sm[0];
}

__global__ __launch_bounds__(1024) void scan2(int* __restrict__ bsum, int nb,
                                              int* __restrict__ totalOut)
{
    __shared__ int sm[1024];
    int t = threadIdx.x;
    sm[t] = (t < nb) ? bsum[t] : 0;
    __syncthreads();
    for (int off = 1; off < 1024; off <<= 1) {
        int u = (t >= off) ? sm[t - off] : 0;
        __syncthreads();
        sm[t] += u;
        __syncthreads();
    }
    if (t < nb) bsum[t] = (t == 0) ? 0 : sm[t - 1];
    if (t == nb - 1) *totalOut = sm[t];
}

__global__ __launch_bounds__(SCAN_B) void scan3(const int* __restrict__ cnt,
                                                const int* __restrict__ bsum,
                                                int* __restrict__ base, int Nn)
{
    __shared__ int sm[SCAN_B];
    int i = blockIdx.x * SCAN_B + threadIdx.x;
    int v = (i < Nn) ? cnt[i] : 0;
    sm[threadIdx.x] = v;
    __syncthreads();
    for (int off = 1; off < SCAN_B; off <<= 1) {
        int u = (threadIdx.x >= off) ? sm[threadIdx.x - off] : 0;
        __syncthreads();
        sm[threadIdx.x] += u;
        __syncthreads();
    }
    if (i < Nn) base[i] = bsum[blockIdx.x] + sm[threadIdx.x] - v;
}

// adjp[pos] = other | (side<<31)   side: 0 = node is parent, 1 = node is child
__global__ __launch_bounds__(256) void fill_k(const int* __restrict__ idx,
                                              int* __restrict__ cursor,
                                              int* __restrict__ adjp, int E)
{
    const int stride = gridDim.x * blockDim.x;
    const int twoE = 2 * E;
    for (int i = blockIdx.x * blockDim.x + threadIdx.x; i < twoE; i += stride) {
        int side  = (i >= E);
        int e     = side ? i - E : i;
        int node  = idx[i];
        int other = side ? idx[e] : idx[E + e];
        int pos = atomicAdd(cursor + node, 1);
        adjp[pos] = other | (side << 31);
    }
}

// ===========================================================================
// per-step fused kernel: one wave per node
//   alpha_e = sigmoid(s1[p]+s2[c]+gb) computed in-register (lane-parallel meta)
//   acc = aP*g1[n] + aC*g2[n] + sum_e alpha_e * (other endpoint's half)
//   h = h + w*relu(acc + h);  h16 = (f16)h;  sOut = h . wg halves
// ===========================================================================
__global__ __launch_bounds__(256) void agg3(const f16* __restrict__ g16,
                                            const int* __restrict__ adjp,
                                            const int* __restrict__ base,
                                            const float* __restrict__ sIn,
                                            float* __restrict__ sOut,
                                            float* __restrict__ h,
                                            f16* __restrict__ h16,
                                            const float* __restrict__ wg,
                                            const float* __restrict__ gbp,
                                            const float* __restrict__ Tp,
                                            float stepf, int Nn)
{
    const int lane = threadIdx.x & 63;
    const int n = (blockIdx.x * blockDim.x + threadIdx.x) >> 6;
    if (n >= Nn) return;
    const float gb = gbp[0];
    const float w  = 1.f / (1.f + expf(-(Tp[0] - stepf)));
    const int b0 = base[n], b1 = base[n + 1];
    const float s1n = sIn[2 * n], s2n = sIn[2 * n + 1];
    const int j0 = lane << 1;

    float ax = 0.f, ay = 0.f, aPl = 0.f, aCl = 0.f;
    for (int c0 = b0; c0 < b1; c0 += 64) {
        const int m = (b1 - c0 < 64) ? (b1 - c0) : 64;
        // lane-parallel edge metadata + alpha
        int meta = adjp[c0 + ((lane < m) ? lane : (m - 1))];
        int other = meta & 0x7FFFFFFF;
        int side  = ((unsigned)meta) >> 31;
        float sv  = sIn[2 * other + (side ^ 1)];
        float aE  = 1.f / (1.f + expf(-((side ? s2n : s1n) + sv + gb)));
        if (lane >= m) aE = 0.f;
        aPl += side ? 0.f : aE;
        aCl += side ? aE : 0.f;

        // batched gathers: 8 independent loads in flight
        int j = 0;
        for (; j + 8 <= m; j += 8) {
            float av[8]; int mv[8];
#pragma unroll
            for (int u = 0; u < 8; ++u) {
                av[u] = __shfl(aE, j + u);
                mv[u] = __shfl(meta, j + u);
            }
            f16x2 gv[8];
#pragma unroll
            for (int u = 0; u < 8; ++u) {
                int ot   = mv[u] & 0x7FFFFFFF;
                int half = (((unsigned)mv[u]) >> 31) ^ 1;
                gv[u] = *(const f16x2*)(g16 + (size_t)ot * 256 + (half << 7) + j0);
            }
#pragma unroll
            for (int u = 0; u < 8; ++u) {
                ax += av[u] * (float)gv[u].x;
                ay += av[u] * (float)gv[u].y;
            }
        }
        for (; j < m; ++j) {
            float a = __shfl(aE, j);
            int mv  = __shfl(meta, j);
            int ot   = mv & 0x7FFFFFFF;
            int half = (((unsigned)mv) >> 31) ^ 1;
            f16x2 gv = *(const f16x2*)(g16 + (size_t)ot * 256 + (half << 7) + j0);
            ax += a * (float)gv.x;
            ay += a * (float)gv.y;
        }
    }

    // totals of alpha by side (all lanes)
    float aP = aPl, aC = aCl;
#pragma unroll
    for (int off = 32; off > 0; off >>= 1) {
        aP += __shfl_xor(aP, off);
        aC += __shfl_xor(aC, off);
    }
    // own-row contribution
    f16x2 o1 = *(const f16x2*)(g16 + (size_t)n * 256 + j0);
    f16x2 o2 = *(const f16x2*)(g16 + (size_t)n * 256 + 128 + j0);
    ax += aP * (float)o1.x + aC * (float)o2.x;
    ay += aP * (float)o1.y + aC * (float)o2.y;

    float2 hv = *(const float2*)(h + (size_t)n * DH + j0);
    hv.x += w * fmaxf(ax + hv.x, 0.f);
    hv.y += w * fmaxf(ay + hv.y, 0.f);
    *(float2*)(h + (size_t)n * DH + j0) = hv;
    f16x2 h2 = {(f16)hv.x, (f16)hv.y};
    *(f16x2*)(h16 + (size_t)n * DH + j0) = h2;

    // next-step gate scalars
    float2 w0 = *(const float2*)(wg + j0);
    float2 w1 = *(const float2*)(wg + 128 + j0);
    float p0 = hv.x * w0.x + hv.y * w0.y;
    float p1 = hv.x * w1.x + hv.y * w1.y;
#pragma unroll
    for (int off = 32; off > 0; off >>= 1) {
        p0 += __shfl_down(p0, off);
        p1 += __shfl_down(p1, off);
    }
    if (lane == 0) { sOut[2 * n] = p0; sOut[2 * n + 1] = p1; }
}

// ---------------------------------------------------------------------------
static inline size_t alignUp(size_t x) { return (x + 255) & ~(size_t)255; }

extern "C" void kernel_launch(void* const* d_in, const int* in_sizes, int n_in,
                              void* d_out, int out_size, void* d_ws, size_t ws_size,
                              hipStream_t stream)
{
    const float* x     = (const float*)d_in[0];
    const int*   idx   = (const int*)d_in[1];
    const float* Ws    = (const float*)d_in[2];
    const float* Wpc   = (const float*)d_in[3];
    const float* Wedge = (const float*)d_in[4];
    const float* Wg    = (const float*)d_in[5];
    const float* Wgb   = (const float*)d_in[6];
    const float* Tp    = (const float*)d_in[7];
    const int Nn = in_sizes[0] / DH;     // 100000
    const int E  = in_sizes[1] / 2;      // 500000
    float* h = (float*)d_out;

    const int nb = (Nn + SCAN_B - 1) / SCAN_B;
    if (nb > 1024) { fprintf(stderr, "kernel_launch: Nn too big for scan\n"); return; }

    // workspace carve-up
    size_t off = 0;
    char* wsb = (char*)d_ws;
    f16*   g16   = (f16*)  (wsb + off); off = alignUp(off + (size_t)Nn * 256 * 2);
    f16*   h16   = (f16*)  (wsb + off); off = alignUp(off + (size_t)Nn * DH * 2);
    f16*   x16   = (f16*)  (wsb + off); off = alignUp(off + (size_t)Nn * DH * 2);
    f16*   Ws16  = (f16*)  (wsb + off); off = alignUp(off + 128 * 128 * 2);
    f16*   Bg16  = (f16*)  (wsb + off); off = alignUp(off + 256 * 128 * 2);
    float* sA    = (float*)(wsb + off); off = alignUp(off + (size_t)Nn * 2 * 4);
    float* sB    = (float*)(wsb + off); off = alignUp(off + (size_t)Nn * 2 * 4);
    int*   cnt   = (int*)  (wsb + off); off = alignUp(off + (size_t)Nn * 4);
    int*   base  = (int*)  (wsb + off); off = alignUp(off + (size_t)(Nn + 1) * 4);
    int*   bsum  = (int*)  (wsb + off); off = alignUp(off + 1024 * 4);
    int*   adjp  = (int*)  (wsb + off); off = alignUp(off + (size_t)(2 * E) * 4);
    if (off > ws_size) {
        fprintf(stderr, "kernel_launch: ws too small (%zu < %zu)\n", ws_size, off);
        return;
    }

    // ---- CSR build + input prep ----
    hipMemsetAsync(cnt, 0, (size_t)Nn * 4, stream);
    prep_k<<<dim3(2048), dim3(256), 0, stream>>>(idx, cnt, 2 * E, x, x16, Nn * DH / 4);
    scan1<<<dim3(nb), dim3(SCAN_B), 0, stream>>>(cnt, bsum, Nn);
    scan2<<<dim3(1), dim3(1024), 0, stream>>>(bsum, nb, base + Nn);
    scan3<<<dim3(nb), dim3(SCAN_B), 0, stream>>>(cnt, bsum, base, Nn);
    hipMemcpyAsync(cnt, base, (size_t)Nn * 4, hipMemcpyDeviceToDevice, stream);
    fill_k<<<dim3(2048), dim3(256), 0, stream>>>(idx, cnt, adjp, E);

    // ---- weights + init h (+ fused s) ----
    wc_kernel<<<dim3(384), dim3(128), 0, stream>>>(Wpc, Wedge, Ws, Bg16, Ws16);
    mfma_gemm_t<128, true, true, true>
        <<<dim3((Nn + 63) / 64), dim3(256), 0, stream>>>(x16, Ws16, h, h16, Wg, sA, Nn);

    // ---- 3 steps ----
    const int aggBlocks = (Nn * 64 + 255) / 256;
    float* sCur = sA; float* sNxt = sB;
    for (int step = 0; step < 3; ++step) {
        mfma_gemm_t<256, false, true, false>
            <<<dim3((Nn + 63) / 64), dim3(256), 0, stream>>>(h16, Bg16, nullptr, g16,
                                                             nullptr, nullptr, Nn);
        agg3<<<dim3(aggBlocks), dim3(256), 0, stream>>>(g16, adjp, base, sCur, sNxt,
                                                        h, h16, Wg, Wgb, Tp,
                                                        (float)step, Nn);
        float* t = sCur; sCur = sNxt; sNxt = t;
    }
}

// Round 5
// 569.197 us; speedup vs baseline: 5.3149x; 1.0134x over previous
//
#include <hip/hip_runtime.h>
#include <cstdio>
#include <cstddef>

#define DH 128

typedef _Float16 f16;
typedef __attribute__((ext_vector_type(8))) _Float16 f16x8;
typedef __attribute__((ext_vector_type(4))) _Float16 f16x4;
typedef __attribute__((ext_vector_type(2))) _Float16 f16x2;
typedef __attribute__((ext_vector_type(4))) float    f32x4;

// ---------------------------------------------------------------------------
// blocks 0..255:  Bg16[o][k] = sum_m Wpc[o&127][m] * Wedge[m][(o<128)? k:128+k]
// blocks 256..383: Ws16 cast
// ---------------------------------------------------------------------------
__global__ __launch_bounds__(128) void wc_kernel(const float* __restrict__ Wpc,
                                                 const float* __restrict__ Wedge,
                                                 const float* __restrict__ Ws,
                                                 f16* __restrict__ Bg16,
                                                 f16* __restrict__ Ws16)
{
    int o = blockIdx.x;
    int k = threadIdx.x;
    if (o < 256) {
        int orow = o & 127;
        int col  = (o < 128) ? k : (128 + k);
        float acc = 0.f;
        for (int m = 0; m < 128; ++m)
            acc += Wpc[orow * 128 + m] * Wedge[m * 256 + col];
        Bg16[o * 128 + k] = (f16)acc;
    } else {
        int row = o - 256;
        Ws16[row * 128 + k] = (f16)Ws[row * 128 + k];
    }
}

// ---------------------------------------------------------------------------
// prep: degree count (atomics) + x -> x16 cast, one grid-stride kernel
// ---------------------------------------------------------------------------
__global__ __launch_bounds__(256) void prep_k(const int* __restrict__ idx,
                                              int* __restrict__ cnt, int twoE,
                                              const float* __restrict__ x,
                                              f16* __restrict__ x16, int n4)
{
    const int stride = gridDim.x * blockDim.x;
    const int mx = (twoE > n4) ? twoE : n4;
    for (int i = blockIdx.x * blockDim.x + threadIdx.x; i < mx; i += stride) {
        if (i < twoE) atomicAdd(cnt + idx[i], 1);
        if (i < n4) {
            float4 v = ((const float4*)x)[i];
            f16x2 a = {(f16)v.x, (f16)v.y};
            f16x2 b = {(f16)v.z, (f16)v.w};
            ((f16x2*)x16)[2 * i]     = a;
            ((f16x2*)x16)[2 * i + 1] = b;
        }
    }
}

// ---------------------------------------------------------------------------
// C[M][OUT] = A16[M][128] @ B16[OUT][128]^T via mfma_f32_16x16x32_f16,
// SWAPPED operands: mfma(B_frag, A_frag) -> lane holds 4 consecutive output
// channels o = ct*16 + kg*4 + j at row m = row0 + (lane&15)  => wide stores.
// Optional fused s = h . wg halves (init path).
// ---------------------------------------------------------------------------
template<int OUT, bool WF32, bool WF16, bool FUSES>
__global__ __launch_bounds__(256) void mfma_gemm_t(const f16* __restrict__ A16,
                                                   const f16* __restrict__ B16,
                                                   float* __restrict__ Cf,
                                                   f16* __restrict__ Ch,
                                                   const float* __restrict__ wg,
                                                   float* __restrict__ s,
                                                   int M)
{
    const int lane = threadIdx.x & 63;
    const int row0 = blockIdx.x * 64 + (threadIdx.x >> 6) * 16;
    const int r = lane & 15, kg = lane >> 4;

    const int m = row0 + r;                  // output row this lane writes
    const bool rowOK = (m < M);
    int arow = m; if (arow > M - 1) arow = M - 1;
    const f16x8* Ap = (const f16x8*)(A16 + (size_t)arow * 128 + kg * 8);
    f16x8 a0 = Ap[0], a1 = Ap[4], a2 = Ap[8], a3 = Ap[12];

    float sp0 = 0.f, sp1 = 0.f;

#pragma unroll 2
    for (int ct = 0; ct < OUT / 16; ++ct) {
        const f16x8* Bp = (const f16x8*)(B16 + (size_t)(ct * 16 + r) * 128 + kg * 8);
        f16x8 b0 = Bp[0], b1 = Bp[4], b2 = Bp[8], b3 = Bp[12];
        f32x4 acc0 = {0.f, 0.f, 0.f, 0.f}, acc1 = {0.f, 0.f, 0.f, 0.f};
        acc0 = __builtin_amdgcn_mfma_f32_16x16x32_f16(b0, a0, acc0, 0, 0, 0);
        acc1 = __builtin_amdgcn_mfma_f32_16x16x32_f16(b2, a2, acc1, 0, 0, 0);
        acc0 = __builtin_amdgcn_mfma_f32_16x16x32_f16(b1, a1, acc0, 0, 0, 0);
        acc1 = __builtin_amdgcn_mfma_f32_16x16x32_f16(b3, a3, acc1, 0, 0, 0);
        const int o0 = ct * 16 + kg * 4;     // 4 consecutive channels
        float v0 = acc0[0] + acc1[0], v1 = acc0[1] + acc1[1];
        float v2 = acc0[2] + acc1[2], v3 = acc0[3] + acc1[3];
        if (rowOK) {
            if constexpr (WF32) {
                float4 fv = make_float4(v0, v1, v2, v3);
                *(float4*)(Cf + (size_t)m * OUT + o0) = fv;
            }
            if constexpr (WF16) {
                f16x4 hv = {(f16)v0, (f16)v1, (f16)v2, (f16)v3};
                *(f16x4*)(Ch + (size_t)m * OUT + o0) = hv;
            }
        }
        if constexpr (FUSES) {
            sp0 += v0 * wg[o0] + v1 * wg[o0 + 1] + v2 * wg[o0 + 2] + v3 * wg[o0 + 3];
            sp1 += v0 * wg[128 + o0] + v1 * wg[128 + o0 + 1] +
                   v2 * wg[128 + o0 + 2] + v3 * wg[128 + o0 + 3];
        }
    }
    if constexpr (FUSES) {
        sp0 += __shfl_xor(sp0, 16); sp0 += __shfl_xor(sp0, 32);
        sp1 += __shfl_xor(sp1, 16); sp1 += __shfl_xor(sp1, 32);
        if (kg == 0 && rowOK) {
            float2 sv = make_float2(sp0, sp1);
            *(float2*)(s + 2 * m) = sv;
        }
    }
}

// ===========================================================================
// CSR build (once per call)
// ===========================================================================
#define SCAN_B 256
__global__ __launch_bounds__(SCAN_B) void scan1(const int* __restrict__ cnt,
                                                int* __restrict__ bsum, int Nn)
{
    __shared__ int sm[SCAN_B];
    int i = blockIdx.x * SCAN_B + threadIdx.x;
    sm[threadIdx.x] = (i < Nn) ? cnt[i] : 0;
    __syncthreads();
    for (int off = SCAN_B / 2; off > 0; off >>= 1) {
        if (threadIdx.x < off) sm[threadIdx.x] += sm[threadIdx.x + off];
        __syncthreads();
    }
    if (threadIdx.x == 0) bsum[blockIdx.x] = sm[0];
}

__global__ __launch_bounds__(1024) void scan2(int* __restrict__ bsum, int nb,
                                              int* __restrict__ totalOut)
{
    __shared__ int sm[1024];
    int t = threadIdx.x;
    sm[t] = (t < nb) ? bsum[t] : 0;
    __syncthreads();
    for (int off = 1; off < 1024; off <<= 1) {
        int u = (t >= off) ? sm[t - off] : 0;
        __syncthreads();
        sm[t] += u;
        __syncthreads();
    }
    if (t < nb) bsum[t] = (t == 0) ? 0 : sm[t - 1];
    if (t == nb - 1) *totalOut = sm[t];
}

// writes exclusive prefix into base AND cursor (saves a d2d memcpy)
__global__ __launch_bounds__(SCAN_B) void scan3(const int* __restrict__ cnt,
                                                const int* __restrict__ bsum,
                                                int* __restrict__ base,
                                                int* __restrict__ cursor, int Nn)
{
    __shared__ int sm[SCAN_B];
    int i = blockIdx.x * SCAN_B + threadIdx.x;
    int v = (i < Nn) ? cnt[i] : 0;
    sm[threadIdx.x] = v;
    __syncthreads();
    for (int off = 1; off < SCAN_B; off <<= 1) {
        int u = (threadIdx.x >= off) ? sm[threadIdx.x - off] : 0;
        __syncthreads();
        sm[threadIdx.x] += u;
        __syncthreads();
    }
    if (i < Nn) {
        int b = bsum[blockIdx.x] + sm[threadIdx.x] - v;
        base[i] = b;
        cursor[i] = b;
    }
}

// adjp[pos] = other | (side<<31)   side: 0 = node is parent, 1 = node is child
__global__ __launch_bounds__(256) void fill_k(const int* __restrict__ idx,
                                              int* __restrict__ cursor,
                                              int* __restrict__ adjp, int E)
{
    const int stride = gridDim.x * blockDim.x;
    const int twoE = 2 * E;
    for (int i = blockIdx.x * blockDim.x + threadIdx.x; i < twoE; i += stride) {
        int side  = (i >= E);
        int e     = side ? i - E : i;
        int node  = idx[i];
        int other = side ? idx[e] : idx[E + e];
        int pos = atomicAdd(cursor + node, 1);
        adjp[pos] = other | (side << 31);
    }
}

// ===========================================================================
// per-step fused kernel: one wave per node, alpha in-register, masked 8-deep
// gather batches (no serial tail; lanes>=m carry aE=0 so clamped shfl is safe)
// ===========================================================================
__global__ __launch_bounds__(256) void agg3(const f16* __restrict__ g16,
                                            const int* __restrict__ adjp,
                                            const int* __restrict__ base,
                                            const float* __restrict__ sIn,
                                            float* __restrict__ sOut,
                                            float* __restrict__ h,
                                            f16* __restrict__ h16,
                                            const float* __restrict__ wg,
                                            const float* __restrict__ gbp,
                                            const float* __restrict__ Tp,
                                            float stepf, int Nn)
{
    const int lane = threadIdx.x & 63;
    const int n = (blockIdx.x * blockDim.x + threadIdx.x) >> 6;
    if (n >= Nn) return;
    const float gb = gbp[0];
    const float w  = 1.f / (1.f + expf(-(Tp[0] - stepf)));
    const int b0 = base[n], b1 = base[n + 1];
    const float s1n = sIn[2 * n], s2n = sIn[2 * n + 1];
    const int j0 = lane << 1;

    // hoisted independent loads
    f16x2 o1 = *(const f16x2*)(g16 + (size_t)n * 256 + j0);
    f16x2 o2 = *(const f16x2*)(g16 + (size_t)n * 256 + 128 + j0);
    float2 hv = *(const float2*)(h + (size_t)n * DH + j0);

    float ax = 0.f, ay = 0.f, aPl = 0.f, aCl = 0.f;
    for (int c0 = b0; c0 < b1; c0 += 64) {
        const int m = (b1 - c0 < 64) ? (b1 - c0) : 64;
        int meta = adjp[c0 + ((lane < m) ? lane : (m - 1))];
        int other = meta & 0x7FFFFFFF;
        int side  = ((unsigned)meta) >> 31;
        float sv  = sIn[2 * other + (side ^ 1)];
        float aE  = 1.f / (1.f + expf(-((side ? s2n : s1n) + sv + gb)));
        if (lane >= m) aE = 0.f;
        aPl += side ? 0.f : aE;
        aCl += side ? aE : 0.f;

        for (int j = 0; j < m; j += 8) {
            float av[8]; int mv[8];
#pragma unroll
            for (int u = 0; u < 8; ++u) {
                int src = j + u; src = (src < 63) ? src : 63;   // masked lanes: aE=0
                av[u] = __shfl(aE, src);
                mv[u] = __shfl(meta, src);
            }
            f16x2 gv[8];
#pragma unroll
            for (int u = 0; u < 8; ++u) {
                int ot   = mv[u] & 0x7FFFFFFF;
                int half = (((unsigned)mv[u]) >> 31) ^ 1;
                gv[u] = *(const f16x2*)(g16 + (size_t)ot * 256 + (half << 7) + j0);
            }
#pragma unroll
            for (int u = 0; u < 8; ++u) {
                ax += av[u] * (float)gv[u].x;
                ay += av[u] * (float)gv[u].y;
            }
        }
    }

    // totals of alpha by side (all lanes)
    float aP = aPl, aC = aCl;
#pragma unroll
    for (int off = 32; off > 0; off >>= 1) {
        aP += __shfl_xor(aP, off);
        aC += __shfl_xor(aC, off);
    }
    // own-row contribution
    ax += aP * (float)o1.x + aC * (float)o2.x;
    ay += aP * (float)o1.y + aC * (float)o2.y;

    hv.x += w * fmaxf(ax + hv.x, 0.f);
    hv.y += w * fmaxf(ay + hv.y, 0.f);
    *(float2*)(h + (size_t)n * DH + j0) = hv;
    f16x2 h2 = {(f16)hv.x, (f16)hv.y};
    *(f16x2*)(h16 + (size_t)n * DH + j0) = h2;

    // next-step gate scalars
    float2 w0 = *(const float2*)(wg + j0);
    float2 w1 = *(const float2*)(wg + 128 + j0);
    float p0 = hv.x * w0.x + hv.y * w0.y;
    float p1 = hv.x * w1.x + hv.y * w1.y;
#pragma unroll
    for (int off = 32; off > 0; off >>= 1) {
        p0 += __shfl_down(p0, off);
        p1 += __shfl_down(p1, off);
    }
    if (lane == 0) { sOut[2 * n] = p0; sOut[2 * n + 1] = p1; }
}

// ---------------------------------------------------------------------------
static inline size_t alignUp(size_t x) { return (x + 255) & ~(size_t)255; }

extern "C" void kernel_launch(void* const* d_in, const int* in_sizes, int n_in,
                              void* d_out, int out_size, void* d_ws, size_t ws_size,
                              hipStream_t stream)
{
    const float* x     = (const float*)d_in[0];
    const int*   idx   = (const int*)d_in[1];
    const float* Ws    = (const float*)d_in[2];
    const float* Wpc   = (const float*)d_in[3];
    const float* Wedge = (const float*)d_in[4];
    const float* Wg    = (const float*)d_in[5];
    const float* Wgb   = (const float*)d_in[6];
    const float* Tp    = (const float*)d_in[7];
    const int Nn = in_sizes[0] / DH;     // 100000
    const int E  = in_sizes[1] / 2;      // 500000
    float* h = (float*)d_out;

    const int nb = (Nn + SCAN_B - 1) / SCAN_B;
    if (nb > 1024) { fprintf(stderr, "kernel_launch: Nn too big for scan\n"); return; }

    // workspace carve-up
    size_t off = 0;
    char* wsb = (char*)d_ws;
    f16*   g16    = (f16*)  (wsb + off); off = alignUp(off + (size_t)Nn * 256 * 2);
    f16*   h16    = (f16*)  (wsb + off); off = alignUp(off + (size_t)Nn * DH * 2);
    f16*   x16    = (f16*)  (wsb + off); off = alignUp(off + (size_t)Nn * DH * 2);
    f16*   Ws16   = (f16*)  (wsb + off); off = alignUp(off + 128 * 128 * 2);
    f16*   Bg16   = (f16*)  (wsb + off); off = alignUp(off + 256 * 128 * 2);
    float* sA     = (float*)(wsb + off); off = alignUp(off + (size_t)Nn * 2 * 4);
    float* sB     = (float*)(wsb + off); off = alignUp(off + (size_t)Nn * 2 * 4);
    int*   cnt    = (int*)  (wsb + off); off = alignUp(off + (size_t)Nn * 4);
    int*   base   = (int*)  (wsb + off); off = alignUp(off + (size_t)(Nn + 1) * 4);
    int*   cursor = (int*)  (wsb + off); off = alignUp(off + (size_t)Nn * 4);
    int*   bsum   = (int*)  (wsb + off); off = alignUp(off + 1024 * 4);
    int*   adjp   = (int*)  (wsb + off); off = alignUp(off + (size_t)(2 * E) * 4);
    if (off > ws_size) {
        fprintf(stderr, "kernel_launch: ws too small (%zu < %zu)\n", ws_size, off);
        return;
    }

    // ---- CSR build + input prep ----
    hipMemsetAsync(cnt, 0, (size_t)Nn * 4, stream);
    prep_k<<<dim3(2048), dim3(256), 0, stream>>>(idx, cnt, 2 * E, x, x16, Nn * DH / 4);
    scan1<<<dim3(nb), dim3(SCAN_B), 0, stream>>>(cnt, bsum, Nn);
    scan2<<<dim3(1), dim3(1024), 0, stream>>>(bsum, nb, base + Nn);
    scan3<<<dim3(nb), dim3(SCAN_B), 0, stream>>>(cnt, bsum, base, cursor, Nn);
    fill_k<<<dim3(2048), dim3(256), 0, stream>>>(idx, cursor, adjp, E);

    // ---- weights + init h (+ fused s) ----
    wc_kernel<<<dim3(384), dim3(128), 0, stream>>>(Wpc, Wedge, Ws, Bg16, Ws16);
    mfma_gemm_t<128, true, true, true>
        <<<dim3((Nn + 63) / 64), dim3(256), 0, stream>>>(x16, Ws16, h, h16, Wg, sA, Nn);

    // ---- 3 steps ----
    const int aggBlocks = (Nn * 64 + 255) / 256;
    float* sCur = sA; float* sNxt = sB;
    for (int step = 0; step < 3; ++step) {
        mfma_gemm_t<256, false, true, false>
            <<<dim3((Nn + 63) / 64), dim3(256), 0, stream>>>(h16, Bg16, nullptr, g16,
                                                             nullptr, nullptr, Nn);
        agg3<<<dim3(aggBlocks), dim3(256), 0, stream>>>(g16, adjp, base, sCur, sNxt,
                                                        h, h16, Wg, Wgb, Tp,
                                                        (float)step, Nn);
        float* t = sCur; sCur = sNxt; sNxt = t;
    }
}

// Round 6
// 535.115 us; speedup vs baseline: 5.6534x; 1.0637x over previous
//
#include <hip/hip_runtime.h>
#include <cstdio>
#include <cstddef>

#define DH 128

typedef _Float16 f16;
typedef __attribute__((ext_vector_type(8))) _Float16 f16x8;
typedef __attribute__((ext_vector_type(4))) _Float16 f16x4;
typedef __attribute__((ext_vector_type(2))) _Float16 f16x2;
typedef __attribute__((ext_vector_type(4))) float    f32x4;

// ---------------------------------------------------------------------------
// blocks 0..255:  Bg16[o][k] = sum_m Wpc[o&127][m] * Wedge[m][(o<128)? k:128+k]
// blocks 256..383: Ws16 cast
// ---------------------------------------------------------------------------
__global__ __launch_bounds__(128) void wc_kernel(const float* __restrict__ Wpc,
                                                 const float* __restrict__ Wedge,
                                                 const float* __restrict__ Ws,
                                                 f16* __restrict__ Bg16,
                                                 f16* __restrict__ Ws16)
{
    int o = blockIdx.x;
    int k = threadIdx.x;
    if (o < 256) {
        int orow = o & 127;
        int col  = (o < 128) ? k : (128 + k);
        float acc = 0.f;
        for (int m = 0; m < 128; ++m)
            acc += Wpc[orow * 128 + m] * Wedge[m * 256 + col];
        Bg16[o * 128 + k] = (f16)acc;
    } else {
        int row = o - 256;
        Ws16[row * 128 + k] = (f16)Ws[row * 128 + k];
    }
}

// ---------------------------------------------------------------------------
// prep: degree count (atomics) + x -> x16 cast, one grid-stride kernel
// ---------------------------------------------------------------------------
__global__ __launch_bounds__(256) void prep_k(const int* __restrict__ idx,
                                              int* __restrict__ cnt, int twoE,
                                              const float* __restrict__ x,
                                              f16* __restrict__ x16, int n4)
{
    const int stride = gridDim.x * blockDim.x;
    const int mx = (twoE > n4) ? twoE : n4;
    for (int i = blockIdx.x * blockDim.x + threadIdx.x; i < mx; i += stride) {
        if (i < twoE) atomicAdd(cnt + idx[i], 1);
        if (i < n4) {
            float4 v = ((const float4*)x)[i];
            f16x2 a = {(f16)v.x, (f16)v.y};
            f16x2 b = {(f16)v.z, (f16)v.w};
            ((f16x2*)x16)[2 * i]     = a;
            ((f16x2*)x16)[2 * i + 1] = b;
        }
    }
}

// ---------------------------------------------------------------------------
// C[M][OUT] = A16[M][128] @ B16[OUT][128]^T via mfma_f32_16x16x32_f16,
// swapped operands: lane holds 4 consecutive channels o = ct*16+kg*4+j at
// row m = row0 + (lane&15). 2 row-tiles (32 rows) per wave -> 8 MFMA/B-load.
// ---------------------------------------------------------------------------
template<int OUT, bool WF32, bool WF16, bool FUSES>
__global__ __launch_bounds__(256) void mfma_gemm_t(const f16* __restrict__ A16,
                                                   const f16* __restrict__ B16,
                                                   float* __restrict__ Cf,
                                                   f16* __restrict__ Ch,
                                                   const float* __restrict__ wg,
                                                   float* __restrict__ s,
                                                   int M)
{
    const int lane = threadIdx.x & 63;
    const int row0 = blockIdx.x * 128 + (threadIdx.x >> 6) * 32;
    const int r = lane & 15, kg = lane >> 4;

    const int mA = row0 + r,      mB = row0 + 16 + r;
    const bool okA = (mA < M),    okB = (mB < M);
    const int arA = okA ? mA : M - 1, arB = okB ? mB : M - 1;
    const f16x8* ApA = (const f16x8*)(A16 + (size_t)arA * 128 + kg * 8);
    const f16x8* ApB = (const f16x8*)(A16 + (size_t)arB * 128 + kg * 8);
    f16x8 a0 = ApA[0], a1 = ApA[4], a2 = ApA[8], a3 = ApA[12];
    f16x8 e0 = ApB[0], e1 = ApB[4], e2 = ApB[8], e3 = ApB[12];

    float spA0 = 0.f, spA1 = 0.f, spB0 = 0.f, spB1 = 0.f;

    for (int ct = 0; ct < OUT / 16; ++ct) {
        const f16x8* Bp = (const f16x8*)(B16 + (size_t)(ct * 16 + r) * 128 + kg * 8);
        f16x8 b0 = Bp[0], b1 = Bp[4], b2 = Bp[8], b3 = Bp[12];
        f32x4 acc0 = {0.f,0.f,0.f,0.f}, acc1 = {0.f,0.f,0.f,0.f};
        f32x4 acc2 = {0.f,0.f,0.f,0.f}, acc3 = {0.f,0.f,0.f,0.f};
        acc0 = __builtin_amdgcn_mfma_f32_16x16x32_f16(b0, a0, acc0, 0, 0, 0);
        acc2 = __builtin_amdgcn_mfma_f32_16x16x32_f16(b0, e0, acc2, 0, 0, 0);
        acc1 = __builtin_amdgcn_mfma_f32_16x16x32_f16(b2, a2, acc1, 0, 0, 0);
        acc3 = __builtin_amdgcn_mfma_f32_16x16x32_f16(b2, e2, acc3, 0, 0, 0);
        acc0 = __builtin_amdgcn_mfma_f32_16x16x32_f16(b1, a1, acc0, 0, 0, 0);
        acc2 = __builtin_amdgcn_mfma_f32_16x16x32_f16(b1, e1, acc2, 0, 0, 0);
        acc1 = __builtin_amdgcn_mfma_f32_16x16x32_f16(b3, a3, acc1, 0, 0, 0);
        acc3 = __builtin_amdgcn_mfma_f32_16x16x32_f16(b3, e3, acc3, 0, 0, 0);

        const int o0 = ct * 16 + kg * 4;
        float vA0 = acc0[0]+acc1[0], vA1 = acc0[1]+acc1[1];
        float vA2 = acc0[2]+acc1[2], vA3 = acc0[3]+acc1[3];
        float vB0 = acc2[0]+acc3[0], vB1 = acc2[1]+acc3[1];
        float vB2 = acc2[2]+acc3[2], vB3 = acc2[3]+acc3[3];
        if (okA) {
            if constexpr (WF32)
                *(float4*)(Cf + (size_t)mA * OUT + o0) = make_float4(vA0, vA1, vA2, vA3);
            if constexpr (WF16) {
                f16x4 hv = {(f16)vA0, (f16)vA1, (f16)vA2, (f16)vA3};
                *(f16x4*)(Ch + (size_t)mA * OUT + o0) = hv;
            }
        }
        if (okB) {
            if constexpr (WF32)
                *(float4*)(Cf + (size_t)mB * OUT + o0) = make_float4(vB0, vB1, vB2, vB3);
            if constexpr (WF16) {
                f16x4 hv = {(f16)vB0, (f16)vB1, (f16)vB2, (f16)vB3};
                *(f16x4*)(Ch + (size_t)mB * OUT + o0) = hv;
            }
        }
        if constexpr (FUSES) {
            float w0 = wg[o0], w1 = wg[o0+1], w2 = wg[o0+2], w3 = wg[o0+3];
            float u0 = wg[128+o0], u1 = wg[128+o0+1], u2 = wg[128+o0+2], u3 = wg[128+o0+3];
            spA0 += vA0*w0 + vA1*w1 + vA2*w2 + vA3*w3;
            spA1 += vA0*u0 + vA1*u1 + vA2*u2 + vA3*u3;
            spB0 += vB0*w0 + vB1*w1 + vB2*w2 + vB3*w3;
            spB1 += vB0*u0 + vB1*u1 + vB2*u2 + vB3*u3;
        }
    }
    if constexpr (FUSES) {
        spA0 += __shfl_xor(spA0, 16); spA0 += __shfl_xor(spA0, 32);
        spA1 += __shfl_xor(spA1, 16); spA1 += __shfl_xor(spA1, 32);
        spB0 += __shfl_xor(spB0, 16); spB0 += __shfl_xor(spB0, 32);
        spB1 += __shfl_xor(spB1, 16); spB1 += __shfl_xor(spB1, 32);
        if (kg == 0) {
            if (okA) *(float2*)(s + 2 * mA) = make_float2(spA0, spA1);
            if (okB) *(float2*)(s + 2 * mB) = make_float2(spB0, spB1);
        }
    }
}

// ===========================================================================
// CSR build (once per call)
// ===========================================================================
#define SCAN_B 256
__global__ __launch_bounds__(SCAN_B) void scan1(const int* __restrict__ cnt,
                                                int* __restrict__ bsum, int Nn)
{
    __shared__ int sm[SCAN_B];
    int i = blockIdx.x * SCAN_B + threadIdx.x;
    sm[threadIdx.x] = (i < Nn) ? cnt[i] : 0;
    __syncthreads();
    for (int off = SCAN_B / 2; off > 0; off >>= 1) {
        if (threadIdx.x < off) sm[threadIdx.x] += sm[threadIdx.x + off];
        __syncthreads();
    }
    if (threadIdx.x == 0) bsum[blockIdx.x] = sm[0];
}

__global__ __launch_bounds__(1024) void scan2(int* __restrict__ bsum, int nb,
                                              int* __restrict__ totalOut)
{
    __shared__ int sm[1024];
    int t = threadIdx.x;
    sm[t] = (t < nb) ? bsum[t] : 0;
    __syncthreads();
    for (int off = 1; off < 1024; off <<= 1) {
        int u = (t >= off) ? sm[t - off] : 0;
        __syncthreads();
        sm[t] += u;
        __syncthreads();
    }
    if (t < nb) bsum[t] = (t == 0) ? 0 : sm[t - 1];
    if (t == nb - 1) *totalOut = sm[t];
}

// writes exclusive prefix into base AND cursor
__global__ __launch_bounds__(SCAN_B) void scan3(const int* __restrict__ cnt,
                                                const int* __restrict__ bsum,
                                                int* __restrict__ base,
                                                int* __restrict__ cursor, int Nn)
{
    __shared__ int sm[SCAN_B];
    int i = blockIdx.x * SCAN_B + threadIdx.x;
    int v = (i < Nn) ? cnt[i] : 0;
    sm[threadIdx.x] = v;
    __syncthreads();
    for (int off = 1; off < SCAN_B; off <<= 1) {
        int u = (threadIdx.x >= off) ? sm[threadIdx.x - off] : 0;
        __syncthreads();
        sm[threadIdx.x] += u;
        __syncthreads();
    }
    if (i < Nn) {
        int b = bsum[blockIdx.x] + sm[threadIdx.x] - v;
        base[i] = b;
        cursor[i] = b;
    }
}

// ---------------------------------------------------------------------------
// XCD-bucketed CSR fill: block group (blockIdx&7) handles node bucket x,
// i.e. nodes with x*Nn <= 8*node < (x+1)*Nn. Each group sweeps the whole edge
// stream but writes only its own contiguous adjp region -> lines fill within
// one XCD's L2 (blockIdx%8 ~ XCD round-robin), killing write amplification.
// Correct regardless of actual XCD mapping (each edge in exactly one bucket).
// adjp[pos] = other | (side<<31)
// ---------------------------------------------------------------------------
__global__ __launch_bounds__(256) void fill_xcd(const int* __restrict__ idx,
                                                int* __restrict__ cursor,
                                                int* __restrict__ adjp,
                                                int E, int Nn)
{
    const int xcd  = blockIdx.x & 7;
    const int gblk = blockIdx.x >> 3;
    const int ngrp = gridDim.x >> 3;
    const int twoE = 2 * E;
    const int lo = xcd * Nn, hi = lo + Nn;   // bucket: lo <= 8*node < hi
    for (int i = gblk * blockDim.x + threadIdx.x; i < twoE; i += ngrp * blockDim.x) {
        int node = idx[i];
        int n8 = node << 3;
        if (n8 < lo || n8 >= hi) continue;
        int side  = (i >= E);
        int e     = side ? i - E : i;
        int other = side ? idx[e] : idx[E + e];
        int pos = atomicAdd(cursor + node, 1);
        adjp[pos] = other | (side << 31);
    }
}

// ===========================================================================
// per-step fused kernel: one wave per node, alpha in-register, 16-deep gather
// pipeline pinned with sched_barrier so loads stay in flight.
// ===========================================================================
__global__ __launch_bounds__(256) void agg3(const f16* __restrict__ g16,
                                            const int* __restrict__ adjp,
                                            const int* __restrict__ base,
                                            const float* __restrict__ sIn,
                                            float* __restrict__ sOut,
                                            float* __restrict__ h,
                                            f16* __restrict__ h16,
                                            const float* __restrict__ wg,
                                            const float* __restrict__ gbp,
                                            const float* __restrict__ Tp,
                                            float stepf, int Nn)
{
    const int lane = threadIdx.x & 63;
    const int n = (blockIdx.x * blockDim.x + threadIdx.x) >> 6;
    if (n >= Nn) return;
    const float gb = gbp[0];
    const float w  = 1.f / (1.f + expf(-(Tp[0] - stepf)));
    const int b0 = base[n], b1 = base[n + 1];
    const float s1n = sIn[2 * n], s2n = sIn[2 * n + 1];
    const int j0 = lane << 1;

    // hoisted independent loads
    f16x2 o1 = *(const f16x2*)(g16 + (size_t)n * 256 + j0);
    f16x2 o2 = *(const f16x2*)(g16 + (size_t)n * 256 + 128 + j0);
    float2 hv = *(const float2*)(h + (size_t)n * DH + j0);

    float ax = 0.f, ay = 0.f, aPl = 0.f, aCl = 0.f;
    for (int c0 = b0; c0 < b1; c0 += 64) {
        const int m = (b1 - c0 < 64) ? (b1 - c0) : 64;
        int meta = adjp[c0 + ((lane < m) ? lane : (m - 1))];
        int other = meta & 0x7FFFFFFF;
        int side  = ((unsigned)meta) >> 31;
        // f16-element offset of gathered half-row (other<2^17 so fits 32b)
        int eoff = (other << 8) | ((side ^ 1) << 7);

        // pre-issue batch 0 (depends only on eoff) -- overlaps alpha compute
        f16x2 gv[16];
#pragma unroll
        for (int u = 0; u < 16; ++u) {
            int eo = __shfl(eoff, u);
            gv[u] = *(const f16x2*)(g16 + (size_t)(unsigned)eo + j0);
        }
        __builtin_amdgcn_sched_barrier(0);

        float sv = sIn[2 * other + (side ^ 1)];
        float aE = 1.f / (1.f + expf(-((side ? s2n : s1n) + sv + gb)));
        if (lane >= m) aE = 0.f;
        aPl += side ? 0.f : aE;
        aCl += side ? aE : 0.f;

        // consume batch 0
#pragma unroll
        for (int u = 0; u < 16; ++u) {
            float av = __shfl(aE, u);
            ax += av * (float)gv[u].x;
            ay += av * (float)gv[u].y;
        }
        // remaining batches (rare: degree > 16)
        for (int j = 16; j < m; j += 16) {
#pragma unroll
            for (int u = 0; u < 16; ++u) {
                int eo = __shfl(eoff, j + u);
                gv[u] = *(const f16x2*)(g16 + (size_t)(unsigned)eo + j0);
            }
            __builtin_amdgcn_sched_barrier(0);
#pragma unroll
            for (int u = 0; u < 16; ++u) {
                float av = __shfl(aE, j + u);
                ax += av * (float)gv[u].x;
                ay += av * (float)gv[u].y;
            }
        }
    }

    // totals of alpha by side (all lanes)
    float aP = aPl, aC = aCl;
#pragma unroll
    for (int off = 32; off > 0; off >>= 1) {
        aP += __shfl_xor(aP, off);
        aC += __shfl_xor(aC, off);
    }
    // own-row contribution
    ax += aP * (float)o1.x + aC * (float)o2.x;
    ay += aP * (float)o1.y + aC * (float)o2.y;

    hv.x += w * fmaxf(ax + hv.x, 0.f);
    hv.y += w * fmaxf(ay + hv.y, 0.f);
    *(float2*)(h + (size_t)n * DH + j0) = hv;
    f16x2 h2 = {(f16)hv.x, (f16)hv.y};
    *(f16x2*)(h16 + (size_t)n * DH + j0) = h2;

    // next-step gate scalars
    float2 w0 = *(const float2*)(wg + j0);
    float2 w1 = *(const float2*)(wg + 128 + j0);
    float p0 = hv.x * w0.x + hv.y * w0.y;
    float p1 = hv.x * w1.x + hv.y * w1.y;
#pragma unroll
    for (int off = 32; off > 0; off >>= 1) {
        p0 += __shfl_down(p0, off);
        p1 += __shfl_down(p1, off);
    }
    if (lane == 0) { sOut[2 * n] = p0; sOut[2 * n + 1] = p1; }
}

// ---------------------------------------------------------------------------
static inline size_t alignUp(size_t x) { return (x + 255) & ~(size_t)255; }

extern "C" void kernel_launch(void* const* d_in, const int* in_sizes, int n_in,
                              void* d_out, int out_size, void* d_ws, size_t ws_size,
                              hipStream_t stream)
{
    const float* x     = (const float*)d_in[0];
    const int*   idx   = (const int*)d_in[1];
    const float* Ws    = (const float*)d_in[2];
    const float* Wpc   = (const float*)d_in[3];
    const float* Wedge = (const float*)d_in[4];
    const float* Wg    = (const float*)d_in[5];
    const float* Wgb   = (const float*)d_in[6];
    const float* Tp    = (const float*)d_in[7];
    const int Nn = in_sizes[0] / DH;     // 100000
    const int E  = in_sizes[1] / 2;      // 500000
    float* h = (float*)d_out;

    const int nb = (Nn + SCAN_B - 1) / SCAN_B;
    if (nb > 1024) { fprintf(stderr, "kernel_launch: Nn too big for scan\n"); return; }

    // workspace carve-up
    size_t off = 0;
    char* wsb = (char*)d_ws;
    f16*   g16    = (f16*)  (wsb + off); off = alignUp(off + (size_t)Nn * 256 * 2);
    f16*   h16    = (f16*)  (wsb + off); off = alignUp(off + (size_t)Nn * DH * 2);
    f16*   x16    = (f16*)  (wsb + off); off = alignUp(off + (size_t)Nn * DH * 2);
    f16*   Ws16   = (f16*)  (wsb + off); off = alignUp(off + 128 * 128 * 2);
    f16*   Bg16   = (f16*)  (wsb + off); off = alignUp(off + 256 * 128 * 2);
    float* sA     = (float*)(wsb + off); off = alignUp(off + (size_t)Nn * 2 * 4);
    float* sB     = (float*)(wsb + off); off = alignUp(off + (size_t)Nn * 2 * 4);
    int*   cnt    = (int*)  (wsb + off); off = alignUp(off + (size_t)Nn * 4);
    int*   base   = (int*)  (wsb + off); off = alignUp(off + (size_t)(Nn + 1) * 4);
    int*   cursor = (int*)  (wsb + off); off = alignUp(off + (size_t)Nn * 4);
    int*   bsum   = (int*)  (wsb + off); off = alignUp(off + 1024 * 4);
    int*   adjp   = (int*)  (wsb + off); off = alignUp(off + (size_t)(2 * E) * 4);
    if (off > ws_size) {
        fprintf(stderr, "kernel_launch: ws too small (%zu < %zu)\n", ws_size, off);
        return;
    }

    // ---- CSR build + input prep ----
    hipMemsetAsync(cnt, 0, (size_t)Nn * 4, stream);
    prep_k<<<dim3(2048), dim3(256), 0, stream>>>(idx, cnt, 2 * E, x, x16, Nn * DH / 4);
    scan1<<<dim3(nb), dim3(SCAN_B), 0, stream>>>(cnt, bsum, Nn);
    scan2<<<dim3(1), dim3(1024), 0, stream>>>(bsum, nb, base + Nn);
    scan3<<<dim3(nb), dim3(SCAN_B), 0, stream>>>(cnt, bsum, base, cursor, Nn);
    fill_xcd<<<dim3(1280), dim3(256), 0, stream>>>(idx, cursor, adjp, E, Nn);

    // ---- weights + init h (+ fused s) ----
    wc_kernel<<<dim3(384), dim3(128), 0, stream>>>(Wpc, Wedge, Ws, Bg16, Ws16);
    mfma_gemm_t<128, true, true, true>
        <<<dim3((Nn + 127) / 128), dim3(256), 0, stream>>>(x16, Ws16, h, h16, Wg, sA, Nn);

    // ---- 3 steps ----
    const int aggBlocks = (Nn * 64 + 255) / 256;
    float* sCur = sA; float* sNxt = sB;
    for (int step = 0; step < 3; ++step) {
        mfma_gemm_t<256, false, true, false>
            <<<dim3((Nn + 127) / 128), dim3(256), 0, stream>>>(h16, Bg16, nullptr, g16,
                                                               nullptr, nullptr, Nn);
        agg3<<<dim3(aggBlocks), dim3(256), 0, stream>>>(g16, adjp, base, sCur, sNxt,
                                                        h, h16, Wg, Wgb, Tp,
                                                        (float)step, Nn);
        float* t = sCur; sCur = sNxt; sNxt = t;
    }
}

// Round 7
// 473.191 us; speedup vs baseline: 6.3933x; 1.1309x over previous
//
#include <hip/hip_runtime.h>
#include <cstdio>
#include <cstddef>

#define DH 128

typedef _Float16 f16;
typedef __attribute__((ext_vector_type(8))) _Float16 f16x8;
typedef __attribute__((ext_vector_type(4))) _Float16 f16x4;
typedef __attribute__((ext_vector_type(2))) _Float16 f16x2;
typedef __attribute__((ext_vector_type(4))) float    f32x4;

// ---------------------------------------------------------------------------
// blocks 0..255:  Bg16[o][k] = sum_m Wpc[o&127][m] * Wedge[m][(o<128)? k:128+k]
// blocks 256..383: Ws16 cast
// ---------------------------------------------------------------------------
__global__ __launch_bounds__(128) void wc_kernel(const float* __restrict__ Wpc,
                                                 const float* __restrict__ Wedge,
                                                 const float* __restrict__ Ws,
                                                 f16* __restrict__ Bg16,
                                                 f16* __restrict__ Ws16)
{
    int o = blockIdx.x;
    int k = threadIdx.x;
    if (o < 256) {
        int orow = o & 127;
        int col  = (o < 128) ? k : (128 + k);
        float acc = 0.f;
        for (int m = 0; m < 128; ++m)
            acc += Wpc[orow * 128 + m] * Wedge[m * 256 + col];
        Bg16[o * 128 + k] = (f16)acc;
    } else {
        int row = o - 256;
        Ws16[row * 128 + k] = (f16)Ws[row * 128 + k];
    }
}

// ---------------------------------------------------------------------------
// prep: degree count (atomics) + x -> x16 cast, one grid-stride kernel
// ---------------------------------------------------------------------------
__global__ __launch_bounds__(256) void prep_k(const int* __restrict__ idx,
                                              int* __restrict__ cnt, int twoE,
                                              const float* __restrict__ x,
                                              f16* __restrict__ x16, int n4)
{
    const int stride = gridDim.x * blockDim.x;
    const int mx = (twoE > n4) ? twoE : n4;
    for (int i = blockIdx.x * blockDim.x + threadIdx.x; i < mx; i += stride) {
        if (i < twoE) atomicAdd(cnt + idx[i], 1);
        if (i < n4) {
            float4 v = ((const float4*)x)[i];
            f16x2 a = {(f16)v.x, (f16)v.y};
            f16x2 b = {(f16)v.z, (f16)v.w};
            ((f16x2*)x16)[2 * i]     = a;
            ((f16x2*)x16)[2 * i + 1] = b;
        }
    }
}

// ---------------------------------------------------------------------------
// C[M][OUT] = A16[M][128] @ B16[OUT][128]^T via mfma_f32_16x16x32_f16,
// swapped operands: lane holds 4 consecutive channels o = ct*16+kg*4+j at
// row m = row0 + (lane&15). 2 row-tiles (32 rows) per wave -> 8 MFMA/B-load.
// ---------------------------------------------------------------------------
template<int OUT, bool WF32, bool WF16, bool FUSES>
__global__ __launch_bounds__(256) void mfma_gemm_t(const f16* __restrict__ A16,
                                                   const f16* __restrict__ B16,
                                                   float* __restrict__ Cf,
                                                   f16* __restrict__ Ch,
                                                   const float* __restrict__ wg,
                                                   float* __restrict__ s,
                                                   int M)
{
    const int lane = threadIdx.x & 63;
    const int row0 = blockIdx.x * 128 + (threadIdx.x >> 6) * 32;
    const int r = lane & 15, kg = lane >> 4;

    const int mA = row0 + r,      mB = row0 + 16 + r;
    const bool okA = (mA < M),    okB = (mB < M);
    const int arA = okA ? mA : M - 1, arB = okB ? mB : M - 1;
    const f16x8* ApA = (const f16x8*)(A16 + (size_t)arA * 128 + kg * 8);
    const f16x8* ApB = (const f16x8*)(A16 + (size_t)arB * 128 + kg * 8);
    f16x8 a0 = ApA[0], a1 = ApA[4], a2 = ApA[8], a3 = ApA[12];
    f16x8 e0 = ApB[0], e1 = ApB[4], e2 = ApB[8], e3 = ApB[12];

    float spA0 = 0.f, spA1 = 0.f, spB0 = 0.f, spB1 = 0.f;

    for (int ct = 0; ct < OUT / 16; ++ct) {
        const f16x8* Bp = (const f16x8*)(B16 + (size_t)(ct * 16 + r) * 128 + kg * 8);
        f16x8 b0 = Bp[0], b1 = Bp[4], b2 = Bp[8], b3 = Bp[12];
        f32x4 acc0 = {0.f,0.f,0.f,0.f}, acc1 = {0.f,0.f,0.f,0.f};
        f32x4 acc2 = {0.f,0.f,0.f,0.f}, acc3 = {0.f,0.f,0.f,0.f};
        acc0 = __builtin_amdgcn_mfma_f32_16x16x32_f16(b0, a0, acc0, 0, 0, 0);
        acc2 = __builtin_amdgcn_mfma_f32_16x16x32_f16(b0, e0, acc2, 0, 0, 0);
        acc1 = __builtin_amdgcn_mfma_f32_16x16x32_f16(b2, a2, acc1, 0, 0, 0);
        acc3 = __builtin_amdgcn_mfma_f32_16x16x32_f16(b2, e2, acc3, 0, 0, 0);
        acc0 = __builtin_amdgcn_mfma_f32_16x16x32_f16(b1, a1, acc0, 0, 0, 0);
        acc2 = __builtin_amdgcn_mfma_f32_16x16x32_f16(b1, e1, acc2, 0, 0, 0);
        acc1 = __builtin_amdgcn_mfma_f32_16x16x32_f16(b3, a3, acc1, 0, 0, 0);
        acc3 = __builtin_amdgcn_mfma_f32_16x16x32_f16(b3, e3, acc3, 0, 0, 0);

        const int o0 = ct * 16 + kg * 4;
        float vA0 = acc0[0]+acc1[0], vA1 = acc0[1]+acc1[1];
        float vA2 = acc0[2]+acc1[2], vA3 = acc0[3]+acc1[3];
        float vB0 = acc2[0]+acc3[0], vB1 = acc2[1]+acc3[1];
        float vB2 = acc2[2]+acc3[2], vB3 = acc2[3]+acc3[3];
        if (okA) {
            if constexpr (WF32)
                *(float4*)(Cf + (size_t)mA * OUT + o0) = make_float4(vA0, vA1, vA2, vA3);
            if constexpr (WF16) {
                f16x4 hv = {(f16)vA0, (f16)vA1, (f16)vA2, (f16)vA3};
                *(f16x4*)(Ch + (size_t)mA * OUT + o0) = hv;
            }
        }
        if (okB) {
            if constexpr (WF32)
                *(float4*)(Cf + (size_t)mB * OUT + o0) = make_float4(vB0, vB1, vB2, vB3);
            if constexpr (WF16) {
                f16x4 hv = {(f16)vB0, (f16)vB1, (f16)vB2, (f16)vB3};
                *(f16x4*)(Ch + (size_t)mB * OUT + o0) = hv;
            }
        }
        if constexpr (FUSES) {
            float w0 = wg[o0], w1 = wg[o0+1], w2 = wg[o0+2], w3 = wg[o0+3];
            float u0 = wg[128+o0], u1 = wg[128+o0+1], u2 = wg[128+o0+2], u3 = wg[128+o0+3];
            spA0 += vA0*w0 + vA1*w1 + vA2*w2 + vA3*w3;
            spA1 += vA0*u0 + vA1*u1 + vA2*u2 + vA3*u3;
            spB0 += vB0*w0 + vB1*w1 + vB2*w2 + vB3*w3;
            spB1 += vB0*u0 + vB1*u1 + vB2*u2 + vB3*u3;
        }
    }
    if constexpr (FUSES) {
        spA0 += __shfl_xor(spA0, 16); spA0 += __shfl_xor(spA0, 32);
        spA1 += __shfl_xor(spA1, 16); spA1 += __shfl_xor(spA1, 32);
        spB0 += __shfl_xor(spB0, 16); spB0 += __shfl_xor(spB0, 32);
        spB1 += __shfl_xor(spB1, 16); spB1 += __shfl_xor(spB1, 32);
        if (kg == 0) {
            if (okA) *(float2*)(s + 2 * mA) = make_float2(spA0, spA1);
            if (okB) *(float2*)(s + 2 * mB) = make_float2(spB0, spB1);
        }
    }
}

// ===========================================================================
// CSR build (once per call)
// ===========================================================================
#define SCAN_B 256
__global__ __launch_bounds__(SCAN_B) void scan1(const int* __restrict__ cnt,
                                                int* __restrict__ bsum, int Nn)
{
    __shared__ int sm[SCAN_B];
    int i = blockIdx.x * SCAN_B + threadIdx.x;
    sm[threadIdx.x] = (i < Nn) ? cnt[i] : 0;
    __syncthreads();
    for (int off = SCAN_B / 2; off > 0; off >>= 1) {
        if (threadIdx.x < off) sm[threadIdx.x] += sm[threadIdx.x + off];
        __syncthreads();
    }
    if (threadIdx.x == 0) bsum[blockIdx.x] = sm[0];
}

__global__ __launch_bounds__(1024) void scan2(int* __restrict__ bsum, int nb,
                                              int* __restrict__ totalOut)
{
    __shared__ int sm[1024];
    int t = threadIdx.x;
    sm[t] = (t < nb) ? bsum[t] : 0;
    __syncthreads();
    for (int off = 1; off < 1024; off <<= 1) {
        int u = (t >= off) ? sm[t - off] : 0;
        __syncthreads();
        sm[t] += u;
        __syncthreads();
    }
    if (t < nb) bsum[t] = (t == 0) ? 0 : sm[t - 1];
    if (t == nb - 1) *totalOut = sm[t];
}

// writes exclusive prefix into base AND cursor
__global__ __launch_bounds__(SCAN_B) void scan3(const int* __restrict__ cnt,
                                                const int* __restrict__ bsum,
                                                int* __restrict__ base,
                                                int* __restrict__ cursor, int Nn)
{
    __shared__ int sm[SCAN_B];
    int i = blockIdx.x * SCAN_B + threadIdx.x;
    int v = (i < Nn) ? cnt[i] : 0;
    sm[threadIdx.x] = v;
    __syncthreads();
    for (int off = 1; off < SCAN_B; off <<= 1) {
        int u = (threadIdx.x >= off) ? sm[threadIdx.x - off] : 0;
        __syncthreads();
        sm[threadIdx.x] += u;
        __syncthreads();
    }
    if (i < Nn) {
        int b = bsum[blockIdx.x] + sm[threadIdx.x] - v;
        base[i] = b;
        cursor[i] = b;
    }
}

// ---------------------------------------------------------------------------
// XCD-bucketed CSR fill (kills scatter write amplification; see R5 notes)
// adjp[pos] = other | (side<<31)
// ---------------------------------------------------------------------------
__global__ __launch_bounds__(256) void fill_xcd(const int* __restrict__ idx,
                                                int* __restrict__ cursor,
                                                int* __restrict__ adjp,
                                                int E, int Nn)
{
    const int xcd  = blockIdx.x & 7;
    const int gblk = blockIdx.x >> 3;
    const int ngrp = gridDim.x >> 3;
    const int twoE = 2 * E;
    const int lo = xcd * Nn, hi = lo + Nn;   // bucket: lo <= 8*node < hi
    for (int i = gblk * blockDim.x + threadIdx.x; i < twoE; i += ngrp * blockDim.x) {
        int node = idx[i];
        int n8 = node << 3;
        if (n8 < lo || n8 >= hi) continue;
        int side  = (i >= E);
        int e     = side ? i - E : i;
        int other = side ? idx[e] : idx[E + e];
        int pos = atomicAdd(cursor + node, 1);
        adjp[pos] = other | (side << 31);
    }
}

// ===========================================================================
// per-step fused kernel: one wave per node; paired-edge f16x4 gathers
// (32 lanes per half-row, lane>>5 selects which of 2 edges), alpha in-reg.
// ===========================================================================
template<bool LAST>
__global__ __launch_bounds__(256) void agg4(const f16* __restrict__ g16,
                                            const int* __restrict__ adjp,
                                            const int* __restrict__ base,
                                            const float* __restrict__ sIn,
                                            float* __restrict__ sOut,
                                            float* __restrict__ h,
                                            f16* __restrict__ h16,
                                            const float* __restrict__ wg,
                                            const float* __restrict__ gbp,
                                            const float* __restrict__ Tp,
                                            float stepf, int Nn)
{
    const int lane = threadIdx.x & 63;
    const int n = (blockIdx.x * blockDim.x + threadIdx.x) >> 6;
    if (n >= Nn) return;
    const float gb = gbp[0];
    const float w  = 1.f / (1.f + expf(-(Tp[0] - stepf)));
    const int b0 = base[n], b1 = base[n + 1];
    const float s1n = sIn[2 * n], s2n = sIn[2 * n + 1];
    const int sub = lane >> 5;          // which edge of the pair
    const int d0  = (lane & 31) << 2;   // element offset (4 per lane)

    // hoisted independent loads (dup across halves; harmless broadcast)
    f16x4 o1 = *(const f16x4*)(g16 + (size_t)n * 256 + d0);
    f16x4 o2 = *(const f16x4*)(g16 + (size_t)n * 256 + 128 + d0);
    float4 hv = *(const float4*)(h + (size_t)n * DH + d0);

    float ax = 0.f, ay = 0.f, az = 0.f, aw = 0.f, aPl = 0.f, aCl = 0.f;
    for (int c0 = b0; c0 < b1; c0 += 64) {
        const int m = (b1 - c0 < 64) ? (b1 - c0) : 64;
        int meta = adjp[c0 + ((lane < m) ? lane : (m - 1))];
        int other = meta & 0x7FFFFFFF;
        int side  = ((unsigned)meta) >> 31;
        int eoff  = (other << 8) | ((side ^ 1) << 7);   // f16 elem offset
        float sv  = sIn[2 * other + (side ^ 1)];
        float aE  = 1.f / (1.f + expf(-((side ? s2n : s1n) + sv + gb)));
        if (lane >= m) aE = 0.f;
        aPl += side ? 0.f : aE;
        aCl += side ? aE : 0.f;

        for (int j = 0; j < m; j += 16) {
            f16x4 gv[8];
#pragma unroll
            for (int u = 0; u < 8; ++u) {
                int es = j + 2 * u + sub; es = (es < 63) ? es : 63;
                int eo = __shfl(eoff, es);
                gv[u] = *(const f16x4*)(g16 + (size_t)(unsigned)eo + d0);
            }
#pragma unroll
            for (int u = 0; u < 8; ++u) {
                int es = j + 2 * u + sub; es = (es < 63) ? es : 63;
                float av = __shfl(aE, es);
                ax += av * (float)gv[u][0];
                ay += av * (float)gv[u][1];
                az += av * (float)gv[u][2];
                aw += av * (float)gv[u][3];
            }
        }
    }

    // combine even/odd edge streams
    ax += __shfl_xor(ax, 32); ay += __shfl_xor(ay, 32);
    az += __shfl_xor(az, 32); aw += __shfl_xor(aw, 32);
    // alpha totals by side
    float aP = aPl, aC = aCl;
#pragma unroll
    for (int off = 32; off > 0; off >>= 1) {
        aP += __shfl_xor(aP, off);
        aC += __shfl_xor(aC, off);
    }
    // own-row contribution
    ax += aP * (float)o1[0] + aC * (float)o2[0];
    ay += aP * (float)o1[1] + aC * (float)o2[1];
    az += aP * (float)o1[2] + aC * (float)o2[2];
    aw += aP * (float)o1[3] + aC * (float)o2[3];

    hv.x += w * fmaxf(ax + hv.x, 0.f);
    hv.y += w * fmaxf(ay + hv.y, 0.f);
    hv.z += w * fmaxf(az + hv.z, 0.f);
    hv.w += w * fmaxf(aw + hv.w, 0.f);

    float p0 = 0.f, p1 = 0.f;
    if (lane < 32) {
        *(float4*)(h + (size_t)n * DH + d0) = hv;
        if constexpr (!LAST) {
            f16x4 h2 = {(f16)hv.x, (f16)hv.y, (f16)hv.z, (f16)hv.w};
            *(f16x4*)(h16 + (size_t)n * DH + d0) = h2;
            float4 w0 = *(const float4*)(wg + d0);
            float4 w1 = *(const float4*)(wg + 128 + d0);
            p0 = hv.x*w0.x + hv.y*w0.y + hv.z*w0.z + hv.w*w0.w;
            p1 = hv.x*w1.x + hv.y*w1.y + hv.z*w1.z + hv.w*w1.w;
        }
    }
    if constexpr (!LAST) {
#pragma unroll
        for (int off = 16; off > 0; off >>= 1) {
            p0 += __shfl_xor(p0, off);
            p1 += __shfl_xor(p1, off);
        }
        if (lane == 0) *(float2*)(sOut + 2 * n) = make_float2(p0, p1);
    }
}

// ---------------------------------------------------------------------------
static inline size_t alignUp(size_t x) { return (x + 255) & ~(size_t)255; }

extern "C" void kernel_launch(void* const* d_in, const int* in_sizes, int n_in,
                              void* d_out, int out_size, void* d_ws, size_t ws_size,
                              hipStream_t stream)
{
    const float* x     = (const float*)d_in[0];
    const int*   idx   = (const int*)d_in[1];
    const float* Ws    = (const float*)d_in[2];
    const float* Wpc   = (const float*)d_in[3];
    const float* Wedge = (const float*)d_in[4];
    const float* Wg    = (const float*)d_in[5];
    const float* Wgb   = (const float*)d_in[6];
    const float* Tp    = (const float*)d_in[7];
    const int Nn = in_sizes[0] / DH;     // 100000
    const int E  = in_sizes[1] / 2;      // 500000
    float* h = (float*)d_out;

    const int nb = (Nn + SCAN_B - 1) / SCAN_B;
    if (nb > 1024) { fprintf(stderr, "kernel_launch: Nn too big for scan\n"); return; }

    // workspace carve-up
    size_t off = 0;
    char* wsb = (char*)d_ws;
    f16*   g16    = (f16*)  (wsb + off); off = alignUp(off + (size_t)Nn * 256 * 2);
    f16*   h16    = (f16*)  (wsb + off); off = alignUp(off + (size_t)Nn * DH * 2);
    f16*   x16    = (f16*)  (wsb + off); off = alignUp(off + (size_t)Nn * DH * 2);
    f16*   Ws16   = (f16*)  (wsb + off); off = alignUp(off + 128 * 128 * 2);
    f16*   Bg16   = (f16*)  (wsb + off); off = alignUp(off + 256 * 128 * 2);
    float* sA     = (float*)(wsb + off); off = alignUp(off + (size_t)Nn * 2 * 4);
    float* sB     = (float*)(wsb + off); off = alignUp(off + (size_t)Nn * 2 * 4);
    int*   cnt    = (int*)  (wsb + off); off = alignUp(off + (size_t)Nn * 4);
    int*   base   = (int*)  (wsb + off); off = alignUp(off + (size_t)(Nn + 1) * 4);
    int*   cursor = (int*)  (wsb + off); off = alignUp(off + (size_t)Nn * 4);
    int*   bsum   = (int*)  (wsb + off); off = alignUp(off + 1024 * 4);
    int*   adjp   = (int*)  (wsb + off); off = alignUp(off + (size_t)(2 * E) * 4);
    if (off > ws_size) {
        fprintf(stderr, "kernel_launch: ws too small (%zu < %zu)\n", ws_size, off);
        return;
    }

    // ---- CSR build + input prep ----
    hipMemsetAsync(cnt, 0, (size_t)Nn * 4, stream);
    prep_k<<<dim3(2048), dim3(256), 0, stream>>>(idx, cnt, 2 * E, x, x16, Nn * DH / 4);
    scan1<<<dim3(nb), dim3(SCAN_B), 0, stream>>>(cnt, bsum, Nn);
    scan2<<<dim3(1), dim3(1024), 0, stream>>>(bsum, nb, base + Nn);
    scan3<<<dim3(nb), dim3(SCAN_B), 0, stream>>>(cnt, bsum, base, cursor, Nn);
    fill_xcd<<<dim3(1280), dim3(256), 0, stream>>>(idx, cursor, adjp, E, Nn);

    // ---- weights + init h (+ fused s) ----
    wc_kernel<<<dim3(384), dim3(128), 0, stream>>>(Wpc, Wedge, Ws, Bg16, Ws16);
    mfma_gemm_t<128, true, true, true>
        <<<dim3((Nn + 127) / 128), dim3(256), 0, stream>>>(x16, Ws16, h, h16, Wg, sA, Nn);

    // ---- 3 steps ----
    const int aggBlocks = (Nn * 64 + 255) / 256;
    float* sCur = sA; float* sNxt = sB;
    for (int step = 0; step < 3; ++step) {
        mfma_gemm_t<256, false, true, false>
            <<<dim3((Nn + 127) / 128), dim3(256), 0, stream>>>(h16, Bg16, nullptr, g16,
                                                               nullptr, nullptr, Nn);
        if (step < 2)
            agg4<false><<<dim3(aggBlocks), dim3(256), 0, stream>>>(g16, adjp, base, sCur,
                                                                   sNxt, h, h16, Wg, Wgb,
                                                                   Tp, (float)step, Nn);
        else
            agg4<true><<<dim3(aggBlocks), dim3(256), 0, stream>>>(g16, adjp, base, sCur,
                                                                  sNxt, h, h16, Wg, Wgb,
                                                                  Tp, (float)step, Nn);
        float* t = sCur; sCur = sNxt; sNxt = t;
    }
}

// Round 9
// 462.109 us; speedup vs baseline: 6.5466x; 1.0240x over previous
//
#include <hip/hip_runtime.h>
#include <cstdio>
#include <cstddef>

#define DH 128

typedef _Float16 f16;
typedef __attribute__((ext_vector_type(8))) _Float16 f16x8;
typedef __attribute__((ext_vector_type(4))) _Float16 f16x4;
typedef __attribute__((ext_vector_type(2))) _Float16 f16x2;
typedef __attribute__((ext_vector_type(4))) float    f32x4;
typedef unsigned int u32;

// ---------------------------------------------------------------------------
// blocks 0..255:  Bg16[o][k] = sum_m Wpc[o&127][m] * Wedge[m][(o<128)? k:128+k]
// blocks 256..383: Ws16 cast
// ---------------------------------------------------------------------------
__global__ __launch_bounds__(128) void wc_kernel(const float* __restrict__ Wpc,
                                                 const float* __restrict__ Wedge,
                                                 const float* __restrict__ Ws,
                                                 f16* __restrict__ Bg16,
                                                 f16* __restrict__ Ws16)
{
    int o = blockIdx.x;
    int k = threadIdx.x;
    if (o < 256) {
        int orow = o & 127;
        int col  = (o < 128) ? k : (128 + k);
        float acc = 0.f;
        for (int m = 0; m < 128; ++m)
            acc += Wpc[orow * 128 + m] * Wedge[m * 256 + col];
        Bg16[o * 128 + k] = (f16)acc;
    } else {
        int row = o - 256;
        Ws16[row * 128 + k] = (f16)Ws[row * 128 + k];
    }
}

// ---------------------------------------------------------------------------
// prep: degree count (atomics) + x -> x16 cast, one grid-stride kernel
// ---------------------------------------------------------------------------
__global__ __launch_bounds__(256) void prep_k(const int* __restrict__ idx,
                                              int* __restrict__ cnt, int twoE,
                                              const float* __restrict__ x,
                                              f16* __restrict__ x16, int n4)
{
    const int stride = gridDim.x * blockDim.x;
    const int mx = (twoE > n4) ? twoE : n4;
    for (int i = blockIdx.x * blockDim.x + threadIdx.x; i < mx; i += stride) {
        if (i < twoE) atomicAdd(cnt + idx[i], 1);
        if (i < n4) {
            float4 v = ((const float4*)x)[i];
            f16x2 a = {(f16)v.x, (f16)v.y};
            f16x2 b = {(f16)v.z, (f16)v.w};
            ((f16x2*)x16)[2 * i]     = a;
            ((f16x2*)x16)[2 * i + 1] = b;
        }
    }
}

// ---------------------------------------------------------------------------
// C[M][OUT] = A16[M][128] @ B16[OUT][128]^T via mfma_f32_16x16x32_f16,
// swapped operands: lane holds 4 consecutive channels o = ct*16+kg*4+j at
// row m = row0 + (lane&15). 2 row-tiles (32 rows) per wave -> 8 MFMA/B-load.
// ---------------------------------------------------------------------------
template<int OUT, bool WF32, bool WF16, bool FUSES>
__global__ __launch_bounds__(256) void mfma_gemm_t(const f16* __restrict__ A16,
                                                   const f16* __restrict__ B16,
                                                   float* __restrict__ Cf,
                                                   f16* __restrict__ Ch,
                                                   const float* __restrict__ wg,
                                                   float* __restrict__ s,
                                                   int M)
{
    const int lane = threadIdx.x & 63;
    const int row0 = blockIdx.x * 128 + (threadIdx.x >> 6) * 32;
    const int r = lane & 15, kg = lane >> 4;

    const int mA = row0 + r,      mB = row0 + 16 + r;
    const bool okA = (mA < M),    okB = (mB < M);
    const int arA = okA ? mA : M - 1, arB = okB ? mB : M - 1;
    const f16x8* ApA = (const f16x8*)(A16 + (size_t)arA * 128 + kg * 8);
    const f16x8* ApB = (const f16x8*)(A16 + (size_t)arB * 128 + kg * 8);
    f16x8 a0 = ApA[0], a1 = ApA[4], a2 = ApA[8], a3 = ApA[12];
    f16x8 e0 = ApB[0], e1 = ApB[4], e2 = ApB[8], e3 = ApB[12];

    float spA0 = 0.f, spA1 = 0.f, spB0 = 0.f, spB1 = 0.f;

    for (int ct = 0; ct < OUT / 16; ++ct) {
        const f16x8* Bp = (const f16x8*)(B16 + (size_t)(ct * 16 + r) * 128 + kg * 8);
        f16x8 b0 = Bp[0], b1 = Bp[4], b2 = Bp[8], b3 = Bp[12];
        f32x4 acc0 = {0.f,0.f,0.f,0.f}, acc1 = {0.f,0.f,0.f,0.f};
        f32x4 acc2 = {0.f,0.f,0.f,0.f}, acc3 = {0.f,0.f,0.f,0.f};
        acc0 = __builtin_amdgcn_mfma_f32_16x16x32_f16(b0, a0, acc0, 0, 0, 0);
        acc2 = __builtin_amdgcn_mfma_f32_16x16x32_f16(b0, e0, acc2, 0, 0, 0);
        acc1 = __builtin_amdgcn_mfma_f32_16x16x32_f16(b2, a2, acc1, 0, 0, 0);
        acc3 = __builtin_amdgcn_mfma_f32_16x16x32_f16(b2, e2, acc3, 0, 0, 0);
        acc0 = __builtin_amdgcn_mfma_f32_16x16x32_f16(b1, a1, acc0, 0, 0, 0);
        acc2 = __builtin_amdgcn_mfma_f32_16x16x32_f16(b1, e1, acc2, 0, 0, 0);
        acc1 = __builtin_amdgcn_mfma_f32_16x16x32_f16(b3, a3, acc1, 0, 0, 0);
        acc3 = __builtin_amdgcn_mfma_f32_16x16x32_f16(b3, e3, acc3, 0, 0, 0);

        const int o0 = ct * 16 + kg * 4;
        float vA0 = acc0[0]+acc1[0], vA1 = acc0[1]+acc1[1];
        float vA2 = acc0[2]+acc1[2], vA3 = acc0[3]+acc1[3];
        float vB0 = acc2[0]+acc3[0], vB1 = acc2[1]+acc3[1];
        float vB2 = acc2[2]+acc3[2], vB3 = acc2[3]+acc3[3];
        if (okA) {
            if constexpr (WF32)
                *(float4*)(Cf + (size_t)mA * OUT + o0) = make_float4(vA0, vA1, vA2, vA3);
            if constexpr (WF16) {
                f16x4 hv = {(f16)vA0, (f16)vA1, (f16)vA2, (f16)vA3};
                *(f16x4*)(Ch + (size_t)mA * OUT + o0) = hv;
            }
        }
        if (okB) {
            if constexpr (WF32)
                *(float4*)(Cf + (size_t)mB * OUT + o0) = make_float4(vB0, vB1, vB2, vB3);
            if constexpr (WF16) {
                f16x4 hv = {(f16)vB0, (f16)vB1, (f16)vB2, (f16)vB3};
                *(f16x4*)(Ch + (size_t)mB * OUT + o0) = hv;
            }
        }
        if constexpr (FUSES) {
            float w0 = wg[o0], w1 = wg[o0+1], w2 = wg[o0+2], w3 = wg[o0+3];
            float u0 = wg[128+o0], u1 = wg[128+o0+1], u2 = wg[128+o0+2], u3 = wg[128+o0+3];
            spA0 += vA0*w0 + vA1*w1 + vA2*w2 + vA3*w3;
            spA1 += vA0*u0 + vA1*u1 + vA2*u2 + vA3*u3;
            spB0 += vB0*w0 + vB1*w1 + vB2*w2 + vB3*w3;
            spB1 += vB0*u0 + vB1*u1 + vB2*u2 + vB3*u3;
        }
    }
    if constexpr (FUSES) {
        spA0 += __shfl_xor(spA0, 16); spA0 += __shfl_xor(spA0, 32);
        spA1 += __shfl_xor(spA1, 16); spA1 += __shfl_xor(spA1, 32);
        spB0 += __shfl_xor(spB0, 16); spB0 += __shfl_xor(spB0, 32);
        spB1 += __shfl_xor(spB1, 16); spB1 += __shfl_xor(spB1, 32);
        if (kg == 0) {
            if (okA) *(float2*)(s + 2 * mA) = make_float2(spA0, spA1);
            if (okB) *(float2*)(s + 2 * mB) = make_float2(spB0, spB1);
        }
    }
}

// ===========================================================================
// CSR build (once per call)
// ===========================================================================
#define SCAN_B 256
__global__ __launch_bounds__(SCAN_B) void scan1(const int* __restrict__ cnt,
                                                int* __restrict__ bsum, int Nn)
{
    __shared__ int sm[SCAN_B];
    int i = blockIdx.x * SCAN_B + threadIdx.x;
    sm[threadIdx.x] = (i < Nn) ? cnt[i] : 0;
    __syncthreads();
    for (int off = SCAN_B / 2; off > 0; off >>= 1) {
        if (threadIdx.x < off) sm[threadIdx.x] += sm[threadIdx.x + off];
        __syncthreads();
    }
    if (threadIdx.x == 0) bsum[blockIdx.x] = sm[0];
}

__global__ __launch_bounds__(1024) void scan2(int* __restrict__ bsum, int nb,
                                              int* __restrict__ totalOut)
{
    __shared__ int sm[1024];
    int t = threadIdx.x;
    sm[t] = (t < nb) ? bsum[t] : 0;
    __syncthreads();
    for (int off = 1; off < 1024; off <<= 1) {
        int u = (t >= off) ? sm[t - off] : 0;
        __syncthreads();
        sm[t] += u;
        __syncthreads();
    }
    if (t < nb) bsum[t] = (t == 0) ? 0 : sm[t - 1];
    if (t == nb - 1) *totalOut = sm[t];
}

// writes exclusive prefix into base AND cursor
__global__ __launch_bounds__(SCAN_B) void scan3(const int* __restrict__ cnt,
                                                const int* __restrict__ bsum,
                                                int* __restrict__ base,
                                                int* __restrict__ cursor, int Nn)
{
    __shared__ int sm[SCAN_B];
    int i = blockIdx.x * SCAN_B + threadIdx.x;
    int v = (i < Nn) ? cnt[i] : 0;
    sm[threadIdx.x] = v;
    __syncthreads();
    for (int off = 1; off < SCAN_B; off <<= 1) {
        int u = (threadIdx.x >= off) ? sm[threadIdx.x - off] : 0;
        __syncthreads();
        sm[threadIdx.x] += u;
        __syncthreads();
    }
    if (i < Nn) {
        int b = bsum[blockIdx.x] + sm[threadIdx.x] - v;
        base[i] = b;
        cursor[i] = b;
    }
}

// ---------------------------------------------------------------------------
// XCD-bucketed CSR fill (kills scatter write amplification; see R5 notes)
// adjp[pos] = other | (side<<31)
// ---------------------------------------------------------------------------
__global__ __launch_bounds__(256) void fill_xcd(const int* __restrict__ idx,
                                                int* __restrict__ cursor,
                                                int* __restrict__ adjp,
                                                int E, int Nn)
{
    const int xcd  = blockIdx.x & 7;
    const int gblk = blockIdx.x >> 3;
    const int ngrp = gridDim.x >> 3;
    const int twoE = 2 * E;
    const int lo = xcd * Nn, hi = lo + Nn;   // bucket: lo <= 8*node < hi
    for (int i = gblk * blockDim.x + threadIdx.x; i < twoE; i += ngrp * blockDim.x) {
        int node = idx[i];
        int n8 = node << 3;
        if (n8 < lo || n8 >= hi) continue;
        int side  = (i >= E);
        int e     = side ? i - E : i;
        int other = side ? idx[e] : idx[E + e];
        int pos = atomicAdd(cursor + node, 1);
        adjp[pos] = other | (side << 31);
    }
}

// ===========================================================================
// per-step fused kernel: one wave per node; paired-edge f16x4 gathers with
// packed-f16 (v_pk_fma_f16) accumulation. Alpha converted+duplicated to a
// pk-operand BEFORE broadcast, so inner loop = 2 shfl + 1 load + 2 pk_fma.
// ===========================================================================
template<bool LAST>
__global__ __launch_bounds__(256) void agg4(const f16* __restrict__ g16,
                                            const int* __restrict__ adjp,
                                            const int* __restrict__ base,
                                            const float* __restrict__ sIn,
                                            float* __restrict__ sOut,
                                            float* __restrict__ h,
                                            f16* __restrict__ h16,
                                            const float* __restrict__ wg,
                                            const float* __restrict__ gbp,
                                            const float* __restrict__ Tp,
                                            float stepf, int Nn)
{
    const int lane = threadIdx.x & 63;
    const int n = (blockIdx.x * blockDim.x + threadIdx.x) >> 6;
    if (n >= Nn) return;
    const float gb = gbp[0];
    const float w  = 1.f / (1.f + expf(-(Tp[0] - stepf)));
    const int b0 = base[n], b1 = base[n + 1];
    const float s1n = sIn[2 * n], s2n = sIn[2 * n + 1];
    const int sub = lane >> 5;          // which edge of the pair
    const int d0  = (lane & 31) << 2;   // element offset (4 per lane)

    // hoisted independent loads (dup across halves; harmless broadcast)
    f16x4 o1 = *(const f16x4*)(g16 + (size_t)n * 256 + d0);
    f16x4 o2 = *(const f16x4*)(g16 + (size_t)n * 256 + 128 + d0);
    float4 hv = *(const float4*)(h + (size_t)n * DH + d0);

    f16x2 accLo = {(f16)0.f, (f16)0.f};
    f16x2 accHi = {(f16)0.f, (f16)0.f};
    float aPl = 0.f, aCl = 0.f;

    union V4 { f16x4 v; f16x2 h2[2]; };
    union AU { u32 w; f16x2 h; unsigned short us[2]; };

    for (int c0 = b0; c0 < b1; c0 += 64) {
        const int m = (b1 - c0 < 64) ? (b1 - c0) : 64;
        int meta = adjp[c0 + ((lane < m) ? lane : (m - 1))];
        int other = meta & 0x7FFFFFFF;
        int side  = ((unsigned)meta) >> 31;
        int eoff  = (other << 8) | ((side ^ 1) << 7);   // f16 elem offset
        float sv  = sIn[2 * other + (side ^ 1)];
        float aE  = 1.f / (1.f + expf(-((side ? s2n : s1n) + sv + gb)));
        if (lane >= m) aE = 0.f;
        aPl += side ? 0.f : aE;
        aCl += side ? aE : 0.f;

        // pack alpha duplicated as 2x f16 for pk_fma broadcast
        AU apk;
        apk.h[0] = (f16)aE;
        apk.us[1] = apk.us[0];

        for (int j = 0; j < m; j += 16) {
            V4 gv[8]; u32 ap[8];
#pragma unroll
            for (int u = 0; u < 8; ++u) {
                int es = j + 2 * u + sub; es = (es < 63) ? es : 63;
                int eo = __shfl(eoff, es);
                ap[u]  = (u32)__shfl((int)apk.w, es);
                gv[u].v = *(const f16x4*)(g16 + (size_t)(unsigned)eo + d0);
            }
#pragma unroll
            for (int u = 0; u < 8; ++u) {
                AU aa; aa.w = ap[u];
                accLo += aa.h * gv[u].h2[0];
                accHi += aa.h * gv[u].h2[1];
            }
        }
    }

    float ax = (float)accLo[0], ay = (float)accLo[1];
    float az = (float)accHi[0], aw = (float)accHi[1];

    // combine even/odd edge streams
    ax += __shfl_xor(ax, 32); ay += __shfl_xor(ay, 32);
    az += __shfl_xor(az, 32); aw += __shfl_xor(aw, 32);
    // alpha totals by side
    float aP = aPl, aC = aCl;
#pragma unroll
    for (int off = 32; off > 0; off >>= 1) {
        aP += __shfl_xor(aP, off);
        aC += __shfl_xor(aC, off);
    }
    // own-row contribution (f32)
    ax += aP * (float)o1[0] + aC * (float)o2[0];
    ay += aP * (float)o1[1] + aC * (float)o2[1];
    az += aP * (float)o1[2] + aC * (float)o2[2];
    aw += aP * (float)o1[3] + aC * (float)o2[3];

    hv.x += w * fmaxf(ax + hv.x, 0.f);
    hv.y += w * fmaxf(ay + hv.y, 0.f);
    hv.z += w * fmaxf(az + hv.z, 0.f);
    hv.w += w * fmaxf(aw + hv.w, 0.f);

    float p0 = 0.f, p1 = 0.f;
    if (lane < 32) {
        *(float4*)(h + (size_t)n * DH + d0) = hv;
        if constexpr (!LAST) {
            f16x4 h2 = {(f16)hv.x, (f16)hv.y, (f16)hv.z, (f16)hv.w};
            *(f16x4*)(h16 + (size_t)n * DH + d0) = h2;
            float4 w0 = *(const float4*)(wg + d0);
            float4 w1 = *(const float4*)(wg + 128 + d0);
            p0 = hv.x*w0.x + hv.y*w0.y + hv.z*w0.z + hv.w*w0.w;
            p1 = hv.x*w1.x + hv.y*w1.y + hv.z*w1.z + hv.w*w1.w;
        }
    }
    if constexpr (!LAST) {
#pragma unroll
        for (int off = 16; off > 0; off >>= 1) {
            p0 += __shfl_xor(p0, off);
            p1 += __shfl_xor(p1, off);
        }
        if (lane == 0) *(float2*)(sOut + 2 * n) = make_float2(p0, p1);
    }
}

// ---------------------------------------------------------------------------
static inline size_t alignUp(size_t x) { return (x + 255) & ~(size_t)255; }

extern "C" void kernel_launch(void* const* d_in, const int* in_sizes, int n_in,
                              void* d_out, int out_size, void* d_ws, size_t ws_size,
                              hipStream_t stream)
{
    const float* x     = (const float*)d_in[0];
    const int*   idx   = (const int*)d_in[1];
    const float* Ws    = (const float*)d_in[2];
    const float* Wpc   = (const float*)d_in[3];
    const float* Wedge = (const float*)d_in[4];
    const float* Wg    = (const float*)d_in[5];
    const float* Wgb   = (const float*)d_in[6];
    const float* Tp    = (const float*)d_in[7];
    const int Nn = in_sizes[0] / DH;     // 100000
    const int E  = in_sizes[1] / 2;      // 500000
    float* h = (float*)d_out;

    const int nb = (Nn + SCAN_B - 1) / SCAN_B;
    if (nb > 1024) { fprintf(stderr, "kernel_launch: Nn too big for scan\n"); return; }

    // workspace carve-up
    size_t off = 0;
    char* wsb = (char*)d_ws;
    f16*   g16    = (f16*)  (wsb + off); off = alignUp(off + (size_t)Nn * 256 * 2);
    f16*   h16    = (f16*)  (wsb + off); off = alignUp(off + (size_t)Nn * DH * 2);
    f16*   x16    = (f16*)  (wsb + off); off = alignUp(off + (size_t)Nn * DH * 2);
    f16*   Ws16   = (f16*)  (wsb + off); off = alignUp(off + 128 * 128 * 2);
    f16*   Bg16   = (f16*)  (wsb + off); off = alignUp(off + 256 * 128 * 2);
    float* sA     = (float*)(wsb + off); off = alignUp(off + (size_t)Nn * 2 * 4);
    float* sB     = (float*)(wsb + off); off = alignUp(off + (size_t)Nn * 2 * 4);
    int*   cnt    = (int*)  (wsb + off); off = alignUp(off + (size_t)Nn * 4);
    int*   base   = (int*)  (wsb + off); off = alignUp(off + (size_t)(Nn + 1) * 4);
    int*   cursor = (int*)  (wsb + off); off = alignUp(off + (size_t)Nn * 4);
    int*   bsum   = (int*)  (wsb + off); off = alignUp(off + 1024 * 4);
    int*   adjp   = (int*)  (wsb + off); off = alignUp(off + (size_t)(2 * E) * 4);
    if (off > ws_size) {
        fprintf(stderr, "kernel_launch: ws too small (%zu < %zu)\n", ws_size, off);
        return;
    }

    // ---- CSR build + input prep ----
    hipMemsetAsync(cnt, 0, (size_t)Nn * 4, stream);
    prep_k<<<dim3(2048), dim3(256), 0, stream>>>(idx, cnt, 2 * E, x, x16, Nn * DH / 4);
    scan1<<<dim3(nb), dim3(SCAN_B), 0, stream>>>(cnt, bsum, Nn);
    scan2<<<dim3(1), dim3(1024), 0, stream>>>(bsum, nb, base + Nn);
    scan3<<<dim3(nb), dim3(SCAN_B), 0, stream>>>(cnt, bsum, base, cursor, Nn);
    fill_xcd<<<dim3(1280), dim3(256), 0, stream>>>(idx, cursor, adjp, E, Nn);

    // ---- weights + init h (+ fused s) ----
    wc_kernel<<<dim3(384), dim3(128), 0, stream>>>(Wpc, Wedge, Ws, Bg16, Ws16);
    mfma_gemm_t<128, true, true, true>
        <<<dim3((Nn + 127) / 128), dim3(256), 0, stream>>>(x16, Ws16, h, h16, Wg, sA, Nn);

    // ---- 3 steps ----
    const int aggBlocks = (Nn * 64 + 255) / 256;
    float* sCur = sA; float* sNxt = sB;
    for (int step = 0; step < 3; ++step) {
        mfma_gemm_t<256, false, true, false>
            <<<dim3((Nn + 127) / 128), dim3(256), 0, stream>>>(h16, Bg16, nullptr, g16,
                                                               nullptr, nullptr, Nn);
        if (step < 2)
            agg4<false><<<dim3(aggBlocks), dim3(256), 0, stream>>>(g16, adjp, base, sCur,
                                                                   sNxt, h, h16, Wg, Wgb,
                                                                   Tp, (float)step, Nn);
        else
            agg4<true><<<dim3(aggBlocks), dim3(256), 0, stream>>>(g16, adjp, base, sCur,
                                                                  sNxt, h, h16, Wg, Wgb,
                                                                  Tp, (float)step, Nn);
        float* t = sCur; sCur = sNxt; sNxt = t;
    }
}

// Round 10
// 450.578 us; speedup vs baseline: 6.7141x; 1.0256x over previous
//
#include <hip/hip_runtime.h>
#include <cstdio>
#include <cstddef>

#define DH 128

typedef _Float16 f16;
typedef __attribute__((ext_vector_type(8))) _Float16 f16x8;
typedef __attribute__((ext_vector_type(4))) _Float16 f16x4;
typedef __attribute__((ext_vector_type(2))) _Float16 f16x2;
typedef __attribute__((ext_vector_type(4))) float    f32x4;
typedef unsigned int u32;

// ---------------------------------------------------------------------------
// blocks 0..255:  Bg16[o][k] = sum_m Wpc[o&127][m] * Wedge[m][(o<128)? k:128+k]
// blocks 256..383: Ws16 cast
// ---------------------------------------------------------------------------
__global__ __launch_bounds__(128) void wc_kernel(const float* __restrict__ Wpc,
                                                 const float* __restrict__ Wedge,
                                                 const float* __restrict__ Ws,
                                                 f16* __restrict__ Bg16,
                                                 f16* __restrict__ Ws16)
{
    int o = blockIdx.x;
    int k = threadIdx.x;
    if (o < 256) {
        int orow = o & 127;
        int col  = (o < 128) ? k : (128 + k);
        float acc = 0.f;
        for (int m = 0; m < 128; ++m)
            acc += Wpc[orow * 128 + m] * Wedge[m * 256 + col];
        Bg16[o * 128 + k] = (f16)acc;
    } else {
        int row = o - 256;
        Ws16[row * 128 + k] = (f16)Ws[row * 128 + k];
    }
}

// ---------------------------------------------------------------------------
// prep: degree count (atomics) + x -> x16 cast, one grid-stride kernel
// ---------------------------------------------------------------------------
__global__ __launch_bounds__(256) void prep_k(const int* __restrict__ idx,
                                              int* __restrict__ cnt, int twoE,
                                              const float* __restrict__ x,
                                              f16* __restrict__ x16, int n4)
{
    const int stride = gridDim.x * blockDim.x;
    const int mx = (twoE > n4) ? twoE : n4;
    for (int i = blockIdx.x * blockDim.x + threadIdx.x; i < mx; i += stride) {
        if (i < twoE) atomicAdd(cnt + idx[i], 1);
        if (i < n4) {
            float4 v = ((const float4*)x)[i];
            f16x2 a = {(f16)v.x, (f16)v.y};
            f16x2 b = {(f16)v.z, (f16)v.w};
            ((f16x2*)x16)[2 * i]     = a;
            ((f16x2*)x16)[2 * i + 1] = b;
        }
    }
}

// ---------------------------------------------------------------------------
// C[M][OUT] = A16[M][128] @ B16[OUT][128]^T via mfma_f32_16x16x32_f16,
// swapped operands; 2 row-tiles (32 rows) per wave; B-prefetch pipeline.
// ---------------------------------------------------------------------------
template<int OUT, bool WF32, bool WF16, bool FUSES>
__global__ __launch_bounds__(256) void mfma_gemm_t(const f16* __restrict__ A16,
                                                   const f16* __restrict__ B16,
                                                   float* __restrict__ Cf,
                                                   f16* __restrict__ Ch,
                                                   const float* __restrict__ wg,
                                                   float* __restrict__ s,
                                                   int M)
{
    const int lane = threadIdx.x & 63;
    const int row0 = blockIdx.x * 128 + (threadIdx.x >> 6) * 32;
    const int r = lane & 15, kg = lane >> 4;

    const int mA = row0 + r,      mB = row0 + 16 + r;
    const bool okA = (mA < M),    okB = (mB < M);
    const int arA = okA ? mA : M - 1, arB = okB ? mB : M - 1;
    const f16x8* ApA = (const f16x8*)(A16 + (size_t)arA * 128 + kg * 8);
    const f16x8* ApB = (const f16x8*)(A16 + (size_t)arB * 128 + kg * 8);
    f16x8 a0 = ApA[0], a1 = ApA[4], a2 = ApA[8], a3 = ApA[12];
    f16x8 e0 = ApB[0], e1 = ApB[4], e2 = ApB[8], e3 = ApB[12];

    float spA0 = 0.f, spA1 = 0.f, spB0 = 0.f, spB1 = 0.f;

    const f16x8* Bp = (const f16x8*)(B16 + (size_t)r * 128 + kg * 8);
    f16x8 b0 = Bp[0], b1 = Bp[4], b2 = Bp[8], b3 = Bp[12];

    for (int ct = 0; ct < OUT / 16; ++ct) {
        // prefetch next B tile before compute
        f16x8 nb0, nb1, nb2, nb3;
        if (ct + 1 < OUT / 16) {
            const f16x8* Bn = (const f16x8*)(B16 + (size_t)((ct + 1) * 16 + r) * 128 + kg * 8);
            nb0 = Bn[0]; nb1 = Bn[4]; nb2 = Bn[8]; nb3 = Bn[12];
        }
        f32x4 acc0 = {0.f,0.f,0.f,0.f}, acc1 = {0.f,0.f,0.f,0.f};
        f32x4 acc2 = {0.f,0.f,0.f,0.f}, acc3 = {0.f,0.f,0.f,0.f};
        acc0 = __builtin_amdgcn_mfma_f32_16x16x32_f16(b0, a0, acc0, 0, 0, 0);
        acc2 = __builtin_amdgcn_mfma_f32_16x16x32_f16(b0, e0, acc2, 0, 0, 0);
        acc1 = __builtin_amdgcn_mfma_f32_16x16x32_f16(b2, a2, acc1, 0, 0, 0);
        acc3 = __builtin_amdgcn_mfma_f32_16x16x32_f16(b2, e2, acc3, 0, 0, 0);
        acc0 = __builtin_amdgcn_mfma_f32_16x16x32_f16(b1, a1, acc0, 0, 0, 0);
        acc2 = __builtin_amdgcn_mfma_f32_16x16x32_f16(b1, e1, acc2, 0, 0, 0);
        acc1 = __builtin_amdgcn_mfma_f32_16x16x32_f16(b3, a3, acc1, 0, 0, 0);
        acc3 = __builtin_amdgcn_mfma_f32_16x16x32_f16(b3, e3, acc3, 0, 0, 0);

        const int o0 = ct * 16 + kg * 4;
        float vA0 = acc0[0]+acc1[0], vA1 = acc0[1]+acc1[1];
        float vA2 = acc0[2]+acc1[2], vA3 = acc0[3]+acc1[3];
        float vB0 = acc2[0]+acc3[0], vB1 = acc2[1]+acc3[1];
        float vB2 = acc2[2]+acc3[2], vB3 = acc2[3]+acc3[3];
        if (okA) {
            if constexpr (WF32)
                *(float4*)(Cf + (size_t)mA * OUT + o0) = make_float4(vA0, vA1, vA2, vA3);
            if constexpr (WF16) {
                f16x4 hv = {(f16)vA0, (f16)vA1, (f16)vA2, (f16)vA3};
                *(f16x4*)(Ch + (size_t)mA * OUT + o0) = hv;
            }
        }
        if (okB) {
            if constexpr (WF32)
                *(float4*)(Cf + (size_t)mB * OUT + o0) = make_float4(vB0, vB1, vB2, vB3);
            if constexpr (WF16) {
                f16x4 hv = {(f16)vB0, (f16)vB1, (f16)vB2, (f16)vB3};
                *(f16x4*)(Ch + (size_t)mB * OUT + o0) = hv;
            }
        }
        if constexpr (FUSES) {
            float w0 = wg[o0], w1 = wg[o0+1], w2 = wg[o0+2], w3 = wg[o0+3];
            float u0 = wg[128+o0], u1 = wg[128+o0+1], u2 = wg[128+o0+2], u3 = wg[128+o0+3];
            spA0 += vA0*w0 + vA1*w1 + vA2*w2 + vA3*w3;
            spA1 += vA0*u0 + vA1*u1 + vA2*u2 + vA3*u3;
            spB0 += vB0*w0 + vB1*w1 + vB2*w2 + vB3*w3;
            spB1 += vB0*u0 + vB1*u1 + vB2*u2 + vB3*u3;
        }
        b0 = nb0; b1 = nb1; b2 = nb2; b3 = nb3;
    }
    if constexpr (FUSES) {
        spA0 += __shfl_xor(spA0, 16); spA0 += __shfl_xor(spA0, 32);
        spA1 += __shfl_xor(spA1, 16); spA1 += __shfl_xor(spA1, 32);
        spB0 += __shfl_xor(spB0, 16); spB0 += __shfl_xor(spB0, 32);
        spB1 += __shfl_xor(spB1, 16); spB1 += __shfl_xor(spB1, 32);
        if (kg == 0) {
            if (okA) *(float2*)(s + 2 * mA) = make_float2(spA0, spA1);
            if (okB) *(float2*)(s + 2 * mB) = make_float2(spB0, spB1);
        }
    }
}

// ===========================================================================
// CSR build (once per call)
// ===========================================================================
#define SCAN_B 256
__global__ __launch_bounds__(SCAN_B) void scan1(const int* __restrict__ cnt,
                                                int* __restrict__ bsum, int Nn)
{
    __shared__ int sm[SCAN_B];
    int i = blockIdx.x * SCAN_B + threadIdx.x;
    sm[threadIdx.x] = (i < Nn) ? cnt[i] : 0;
    __syncthreads();
    for (int off = SCAN_B / 2; off > 0; off >>= 1) {
        if (threadIdx.x < off) sm[threadIdx.x] += sm[threadIdx.x + off];
        __syncthreads();
    }
    if (threadIdx.x == 0) bsum[blockIdx.x] = sm[0];
}

__global__ __launch_bounds__(1024) void scan2(int* __restrict__ bsum, int nb,
                                              int* __restrict__ totalOut)
{
    __shared__ int sm[1024];
    int t = threadIdx.x;
    sm[t] = (t < nb) ? bsum[t] : 0;
    __syncthreads();
    for (int off = 1; off < 1024; off <<= 1) {
        int u = (t >= off) ? sm[t - off] : 0;
        __syncthreads();
        sm[t] += u;
        __syncthreads();
    }
    if (t < nb) bsum[t] = (t == 0) ? 0 : sm[t - 1];
    if (t == nb - 1) *totalOut = sm[t];
}

// writes exclusive prefix into base AND cursor
__global__ __launch_bounds__(SCAN_B) void scan3(const int* __restrict__ cnt,
                                                const int* __restrict__ bsum,
                                                int* __restrict__ base,
                                                int* __restrict__ cursor, int Nn)
{
    __shared__ int sm[SCAN_B];
    int i = blockIdx.x * SCAN_B + threadIdx.x;
    int v = (i < Nn) ? cnt[i] : 0;
    sm[threadIdx.x] = v;
    __syncthreads();
    for (int off = 1; off < SCAN_B; off <<= 1) {
        int u = (threadIdx.x >= off) ? sm[threadIdx.x - off] : 0;
        __syncthreads();
        sm[threadIdx.x] += u;
        __syncthreads();
    }
    if (i < Nn) {
        int b = bsum[blockIdx.x] + sm[threadIdx.x] - v;
        base[i] = b;
        cursor[i] = b;
    }
}

// ---------------------------------------------------------------------------
// XCD-bucketed CSR fill (kills scatter write amplification; see R5 notes)
// adjp[pos] = other | (side<<31)
// ---------------------------------------------------------------------------
__global__ __launch_bounds__(256) void fill_xcd(const int* __restrict__ idx,
                                                int* __restrict__ cursor,
                                                int* __restrict__ adjp,
                                                int E, int Nn)
{
    const int xcd  = blockIdx.x & 7;
    const int gblk = blockIdx.x >> 3;
    const int ngrp = gridDim.x >> 3;
    const int twoE = 2 * E;
    const int lo = xcd * Nn, hi = lo + Nn;   // bucket: lo <= 8*node < hi
    for (int i = gblk * blockDim.x + threadIdx.x; i < twoE; i += ngrp * blockDim.x) {
        int node = idx[i];
        int n8 = node << 3;
        if (n8 < lo || n8 >= hi) continue;
        int side  = (i >= E);
        int e     = side ? i - E : i;
        int other = side ? idx[e] : idx[E + e];
        int pos = atomicAdd(cursor + node, 1);
        adjp[pos] = other | (side << 31);
    }
}

// ===========================================================================
// per-step fused kernel: TWO nodes per wave (32-lane groups). A group's 32
// lanes cover one 256B half-row (8B/lane); prologue/epilogue amortize over
// 2 nodes. Wave-uniform while(__any) loop; masked groups carry alpha=0.
// ===========================================================================
template<bool LAST>
__global__ __launch_bounds__(256) void agg6(const f16* __restrict__ g16,
                                            const int* __restrict__ adjp,
                                            const int* __restrict__ base,
                                            const float* __restrict__ sIn,
                                            float* __restrict__ sOut,
                                            float* __restrict__ h,
                                            f16* __restrict__ h16,
                                            const float* __restrict__ wg,
                                            const float* __restrict__ gbp,
                                            const float* __restrict__ Tp,
                                            float stepf, int Nn, int twoE)
{
    const int lane = threadIdx.x & 63;
    const int grp  = lane >> 5;          // node slot within wave
    const int gl   = lane & 31;          // lane within group
    const int wvid = (blockIdx.x * blockDim.x + threadIdx.x) >> 6;
    int n = wvid * 2 + grp;
    const bool nOK = (n < Nn);
    if (n >= Nn) n = Nn - 1;             // clamp; writes guarded by nOK
    const float gb = gbp[0];
    const float w  = 1.f / (1.f + expf(-(Tp[0] - stepf)));
    const int b0 = base[n], b1 = base[n + 1];
    const int deg = b1 - b0;
    const float s1n = sIn[2 * n], s2n = sIn[2 * n + 1];
    const int d0 = gl << 2;              // f16 elem offset (4 elems = 8B/lane)

    // hoisted independent loads
    f16x4 o1 = *(const f16x4*)(g16 + (size_t)n * 256 + d0);
    f16x4 o2 = *(const f16x4*)(g16 + (size_t)n * 256 + 128 + d0);
    float4 hv = *(const float4*)(h + (size_t)n * DH + d0);

    f16x2 accLo = {(f16)0.f, (f16)0.f};
    f16x2 accHi = {(f16)0.f, (f16)0.f};
    float aPl = 0.f, aCl = 0.f;

    union V4 { f16x4 v; f16x2 h2[2]; };
    union AU { u32 w; f16x2 h; unsigned short us[2]; };

    int t = 0;
    while (__any(t * 32 < deg)) {
        const int done = t * 32;
        int m = deg - done; m = (m < 0) ? 0 : ((m > 32) ? 32 : m);
        int midx = b0 + done + ((gl < m) ? gl : ((m > 0) ? m - 1 : 0));
        midx = (midx < twoE - 1) ? midx : (twoE - 1);
        midx = (midx > 0) ? midx : 0;
        int meta  = adjp[midx];
        int other = meta & 0x7FFFFFFF;
        int side  = ((unsigned)meta) >> 31;
        int eoff  = (other << 8) | ((side ^ 1) << 7);   // f16 elem offset
        float sv  = sIn[2 * other + (side ^ 1)];
        float aE  = 1.f / (1.f + expf(-((side ? s2n : s1n) + sv + gb)));
        if (gl >= m) aE = 0.f;
        aPl += side ? 0.f : aE;
        aCl += side ? aE : 0.f;

        AU apk;
        apk.h[0] = (f16)aE;
        apk.us[1] = apk.us[0];

        const int sb = grp << 5;         // group's shfl base
        for (int j = 0; j < m; j += 8) {
            V4 gv[8]; u32 ap[8];
#pragma unroll
            for (int u = 0; u < 8; ++u) {
                int es = j + u; es = (es < 31) ? es : 31;
                int eo = __shfl(eoff, sb | es);
                ap[u]  = (u32)__shfl((int)apk.w, sb | es);
                gv[u].v = *(const f16x4*)(g16 + (size_t)(unsigned)eo + d0);
            }
#pragma unroll
            for (int u = 0; u < 8; ++u) {
                AU aa; aa.w = ap[u];
                accLo += aa.h * gv[u].h2[0];
                accHi += aa.h * gv[u].h2[1];
            }
        }
        ++t;
    }

    float ax = (float)accLo[0], ay = (float)accLo[1];
    float az = (float)accHi[0], aw = (float)accHi[1];

    // alpha totals by side (group-local butterflies)
    float aP = aPl, aC = aCl;
#pragma unroll
    for (int off = 16; off > 0; off >>= 1) {
        aP += __shfl_xor(aP, off);
        aC += __shfl_xor(aC, off);
    }
    // own-row contribution (f32)
    ax += aP * (float)o1[0] + aC * (float)o2[0];
    ay += aP * (float)o1[1] + aC * (float)o2[1];
    az += aP * (float)o1[2] + aC * (float)o2[2];
    aw += aP * (float)o1[3] + aC * (float)o2[3];

    hv.x += w * fmaxf(ax + hv.x, 0.f);
    hv.y += w * fmaxf(ay + hv.y, 0.f);
    hv.z += w * fmaxf(az + hv.z, 0.f);
    hv.w += w * fmaxf(aw + hv.w, 0.f);

    float p0 = 0.f, p1 = 0.f;
    if (nOK) {
        *(float4*)(h + (size_t)n * DH + d0) = hv;
        if constexpr (!LAST) {
            f16x4 h2 = {(f16)hv.x, (f16)hv.y, (f16)hv.z, (f16)hv.w};
            *(f16x4*)(h16 + (size_t)n * DH + d0) = h2;
        }
    }
    if constexpr (!LAST) {
        float4 w0 = *(const float4*)(wg + d0);
        float4 w1 = *(const float4*)(wg + 128 + d0);
        p0 = hv.x*w0.x + hv.y*w0.y + hv.z*w0.z + hv.w*w0.w;
        p1 = hv.x*w1.x + hv.y*w1.y + hv.z*w1.z + hv.w*w1.w;
#pragma unroll
        for (int off = 16; off > 0; off >>= 1) {
            p0 += __shfl_xor(p0, off);
            p1 += __shfl_xor(p1, off);
        }
        if (gl == 0 && nOK) *(float2*)(sOut + 2 * n) = make_float2(p0, p1);
    }
}

// ---------------------------------------------------------------------------
static inline size_t alignUp(size_t x) { return (x + 255) & ~(size_t)255; }

extern "C" void kernel_launch(void* const* d_in, const int* in_sizes, int n_in,
                              void* d_out, int out_size, void* d_ws, size_t ws_size,
                              hipStream_t stream)
{
    const float* x     = (const float*)d_in[0];
    const int*   idx   = (const int*)d_in[1];
    const float* Ws    = (const float*)d_in[2];
    const float* Wpc   = (const float*)d_in[3];
    const float* Wedge = (const float*)d_in[4];
    const float* Wg    = (const float*)d_in[5];
    const float* Wgb   = (const float*)d_in[6];
    const float* Tp    = (const float*)d_in[7];
    const int Nn = in_sizes[0] / DH;     // 100000
    const int E  = in_sizes[1] / 2;      // 500000
    float* h = (float*)d_out;

    const int nb = (Nn + SCAN_B - 1) / SCAN_B;
    if (nb > 1024) { fprintf(stderr, "kernel_launch: Nn too big for scan\n"); return; }

    // workspace carve-up
    size_t off = 0;
    char* wsb = (char*)d_ws;
    f16*   g16    = (f16*)  (wsb + off); off = alignUp(off + (size_t)Nn * 256 * 2);
    f16*   h16    = (f16*)  (wsb + off); off = alignUp(off + (size_t)Nn * DH * 2);
    f16*   x16    = (f16*)  (wsb + off); off = alignUp(off + (size_t)Nn * DH * 2);
    f16*   Ws16   = (f16*)  (wsb + off); off = alignUp(off + 128 * 128 * 2);
    f16*   Bg16   = (f16*)  (wsb + off); off = alignUp(off + 256 * 128 * 2);
    float* sA     = (float*)(wsb + off); off = alignUp(off + (size_t)Nn * 2 * 4);
    float* sB     = (float*)(wsb + off); off = alignUp(off + (size_t)Nn * 2 * 4);
    int*   cnt    = (int*)  (wsb + off); off = alignUp(off + (size_t)Nn * 4);
    int*   base   = (int*)  (wsb + off); off = alignUp(off + (size_t)(Nn + 1) * 4);
    int*   cursor = (int*)  (wsb + off); off = alignUp(off + (size_t)Nn * 4);
    int*   bsum   = (int*)  (wsb + off); off = alignUp(off + 1024 * 4);
    int*   adjp   = (int*)  (wsb + off); off = alignUp(off + (size_t)(2 * E + 64) * 4);
    if (off > ws_size) {
        fprintf(stderr, "kernel_launch: ws too small (%zu < %zu)\n", ws_size, off);
        return;
    }

    // ---- CSR build + input prep ----
    hipMemsetAsync(cnt, 0, (size_t)Nn * 4, stream);
    prep_k<<<dim3(2048), dim3(256), 0, stream>>>(idx, cnt, 2 * E, x, x16, Nn * DH / 4);
    scan1<<<dim3(nb), dim3(SCAN_B), 0, stream>>>(cnt, bsum, Nn);
    scan2<<<dim3(1), dim3(1024), 0, stream>>>(bsum, nb, base + Nn);
    scan3<<<dim3(nb), dim3(SCAN_B), 0, stream>>>(cnt, bsum, base, cursor, Nn);
    fill_xcd<<<dim3(1280), dim3(256), 0, stream>>>(idx, cursor, adjp, E, Nn);

    // ---- weights + init h (+ fused s) ----
    wc_kernel<<<dim3(384), dim3(128), 0, stream>>>(Wpc, Wedge, Ws, Bg16, Ws16);
    mfma_gemm_t<128, true, true, true>
        <<<dim3((Nn + 127) / 128), dim3(256), 0, stream>>>(x16, Ws16, h, h16, Wg, sA, Nn);

    // ---- 3 steps ----
    const int aggBlocks = (Nn * 32 + 255) / 256;
    float* sCur = sA; float* sNxt = sB;
    for (int step = 0; step < 3; ++step) {
        mfma_gemm_t<256, false, true, false>
            <<<dim3((Nn + 127) / 128), dim3(256), 0, stream>>>(h16, Bg16, nullptr, g16,
                                                               nullptr, nullptr, Nn);
        if (step < 2)
            agg6<false><<<dim3(aggBlocks), dim3(256), 0, stream>>>(g16, adjp, base, sCur,
                                                                   sNxt, h, h16, Wg, Wgb,
                                                                   Tp, (float)step, Nn, 2 * E);
        else
            agg6<true><<<dim3(aggBlocks), dim3(256), 0, stream>>>(g16, adjp, base, sCur,
                                                                  sNxt, h, h16, Wg, Wgb,
                                                                  Tp, (float)step, Nn, 2 * E);
        float* t = sCur; sCur = sNxt; sNxt = t;
    }
}

// Round 11
// 415.319 us; speedup vs baseline: 7.2841x; 1.0849x over previous
//
#include <hip/hip_runtime.h>
#include <cstdio>
#include <cstddef>

#define DH 128

typedef _Float16 f16;
typedef __attribute__((ext_vector_type(8))) _Float16 f16x8;
typedef __attribute__((ext_vector_type(4))) _Float16 f16x4;
typedef __attribute__((ext_vector_type(2))) _Float16 f16x2;
typedef __attribute__((ext_vector_type(4))) float    f32x4;
typedef unsigned int u32;

// ---------------------------------------------------------------------------
// blocks 0..255:  Bg16[o][k] = sum_m Wpc[o&127][m] * Wedge[m][(o<128)? k:128+k]
// blocks 256..383: Ws16 cast
// ---------------------------------------------------------------------------
__global__ __launch_bounds__(128) void wc_kernel(const float* __restrict__ Wpc,
                                                 const float* __restrict__ Wedge,
                                                 const float* __restrict__ Ws,
                                                 f16* __restrict__ Bg16,
                                                 f16* __restrict__ Ws16)
{
    int o = blockIdx.x;
    int k = threadIdx.x;
    if (o < 256) {
        int orow = o & 127;
        int col  = (o < 128) ? k : (128 + k);
        float acc = 0.f;
        for (int m = 0; m < 128; ++m)
            acc += Wpc[orow * 128 + m] * Wedge[m * 256 + col];
        Bg16[o * 128 + k] = (f16)acc;
    } else {
        int row = o - 256;
        Ws16[row * 128 + k] = (f16)Ws[row * 128 + k];
    }
}

// ---------------------------------------------------------------------------
// prep: degree count (atomics) + x -> x16 cast, one grid-stride kernel
// ---------------------------------------------------------------------------
__global__ __launch_bounds__(256) void prep_k(const int* __restrict__ idx,
                                              int* __restrict__ cnt, int twoE,
                                              const float* __restrict__ x,
                                              f16* __restrict__ x16, int n4)
{
    const int stride = gridDim.x * blockDim.x;
    const int mx = (twoE > n4) ? twoE : n4;
    for (int i = blockIdx.x * blockDim.x + threadIdx.x; i < mx; i += stride) {
        if (i < twoE) atomicAdd(cnt + idx[i], 1);
        if (i < n4) {
            float4 v = ((const float4*)x)[i];
            f16x2 a = {(f16)v.x, (f16)v.y};
            f16x2 b = {(f16)v.z, (f16)v.w};
            ((f16x2*)x16)[2 * i]     = a;
            ((f16x2*)x16)[2 * i + 1] = b;
        }
    }
}

// ---------------------------------------------------------------------------
// C[M][OUT] = A16[M][128] @ B16[OUT][128]^T via mfma_f32_16x16x32_f16,
// swapped operands: lane holds 4 consecutive channels o = ct*16+kg*4+j at
// row m. NT row-tiles (NT*16 rows) per wave: per ct, 4 B-loads feed NT*4 MFMA.
// ---------------------------------------------------------------------------
template<int OUT, int NT, bool WF32, bool WF16, bool FUSES>
__global__ __launch_bounds__(256) void mfma_gemm_t(const f16* __restrict__ A16,
                                                   const f16* __restrict__ B16,
                                                   float* __restrict__ Cf,
                                                   f16* __restrict__ Ch,
                                                   const float* __restrict__ wg,
                                                   float* __restrict__ s,
                                                   int M)
{
    const int lane = threadIdx.x & 63;
    const int row0 = blockIdx.x * (NT * 64) + (threadIdx.x >> 6) * (NT * 16);
    const int r = lane & 15, kg = lane >> 4;

    int  mrow[NT];
    bool ok[NT];
    f16x8 a[NT][4];
#pragma unroll
    for (int t = 0; t < NT; ++t) {
        mrow[t] = row0 + t * 16 + r;
        ok[t]   = (mrow[t] < M);
        int ar  = ok[t] ? mrow[t] : M - 1;
        const f16x8* Ap = (const f16x8*)(A16 + (size_t)ar * 128 + kg * 8);
        a[t][0] = Ap[0]; a[t][1] = Ap[4]; a[t][2] = Ap[8]; a[t][3] = Ap[12];
    }

    float sp0[NT], sp1[NT];
    if constexpr (FUSES) {
#pragma unroll
        for (int t = 0; t < NT; ++t) { sp0[t] = 0.f; sp1[t] = 0.f; }
    }

    for (int ct = 0; ct < OUT / 16; ++ct) {
        const f16x8* Bp = (const f16x8*)(B16 + (size_t)(ct * 16 + r) * 128 + kg * 8);
        f16x8 b0 = Bp[0], b1 = Bp[4], b2 = Bp[8], b3 = Bp[12];
        const int o0 = ct * 16 + kg * 4;
        float w0, w1, w2, w3, u0, u1, u2, u3;
        if constexpr (FUSES) {
            w0 = wg[o0]; w1 = wg[o0+1]; w2 = wg[o0+2]; w3 = wg[o0+3];
            u0 = wg[128+o0]; u1 = wg[128+o0+1]; u2 = wg[128+o0+2]; u3 = wg[128+o0+3];
        }
#pragma unroll
        for (int t = 0; t < NT; ++t) {
            f32x4 acc = {0.f, 0.f, 0.f, 0.f};
            acc = __builtin_amdgcn_mfma_f32_16x16x32_f16(b0, a[t][0], acc, 0, 0, 0);
            acc = __builtin_amdgcn_mfma_f32_16x16x32_f16(b1, a[t][1], acc, 0, 0, 0);
            acc = __builtin_amdgcn_mfma_f32_16x16x32_f16(b2, a[t][2], acc, 0, 0, 0);
            acc = __builtin_amdgcn_mfma_f32_16x16x32_f16(b3, a[t][3], acc, 0, 0, 0);
            if (ok[t]) {
                if constexpr (WF32)
                    *(float4*)(Cf + (size_t)mrow[t] * OUT + o0) =
                        make_float4(acc[0], acc[1], acc[2], acc[3]);
                if constexpr (WF16) {
                    f16x4 hv = {(f16)acc[0], (f16)acc[1], (f16)acc[2], (f16)acc[3]};
                    *(f16x4*)(Ch + (size_t)mrow[t] * OUT + o0) = hv;
                }
            }
            if constexpr (FUSES) {
                sp0[t] += acc[0]*w0 + acc[1]*w1 + acc[2]*w2 + acc[3]*w3;
                sp1[t] += acc[0]*u0 + acc[1]*u1 + acc[2]*u2 + acc[3]*u3;
            }
        }
    }
    if constexpr (FUSES) {
#pragma unroll
        for (int t = 0; t < NT; ++t) {
            float p0 = sp0[t], p1 = sp1[t];
            p0 += __shfl_xor(p0, 16); p0 += __shfl_xor(p0, 32);
            p1 += __shfl_xor(p1, 16); p1 += __shfl_xor(p1, 32);
            if (kg == 0 && ok[t])
                *(float2*)(s + 2 * mrow[t]) = make_float2(p0, p1);
        }
    }
}

// ===========================================================================
// CSR build (once per call)
// ===========================================================================
#define SCAN_B 256
__global__ __launch_bounds__(SCAN_B) void scan1(const int* __restrict__ cnt,
                                                int* __restrict__ bsum, int Nn)
{
    __shared__ int sm[SCAN_B];
    int i = blockIdx.x * SCAN_B + threadIdx.x;
    sm[threadIdx.x] = (i < Nn) ? cnt[i] : 0;
    __syncthreads();
    for (int off = SCAN_B / 2; off > 0; off >>= 1) {
        if (threadIdx.x < off) sm[threadIdx.x] += sm[threadIdx.x + off];
        __syncthreads();
    }
    if (threadIdx.x == 0) bsum[blockIdx.x] = sm[0];
}

__global__ __launch_bounds__(1024) void scan2(int* __restrict__ bsum, int nb,
                                              int* __restrict__ totalOut)
{
    __shared__ int sm[1024];
    int t = threadIdx.x;
    sm[t] = (t < nb) ? bsum[t] : 0;
    __syncthreads();
    for (int off = 1; off < 1024; off <<= 1) {
        int u = (t >= off) ? sm[t - off] : 0;
        __syncthreads();
        sm[t] += u;
        __syncthreads();
    }
    if (t < nb) bsum[t] = (t == 0) ? 0 : sm[t - 1];
    if (t == nb - 1) *totalOut = sm[t];
}

// writes exclusive prefix into base AND cursor
__global__ __launch_bounds__(SCAN_B) void scan3(const int* __restrict__ cnt,
                                                const int* __restrict__ bsum,
                                                int* __restrict__ base,
                                                int* __restrict__ cursor, int Nn)
{
    __shared__ int sm[SCAN_B];
    int i = blockIdx.x * SCAN_B + threadIdx.x;
    int v = (i < Nn) ? cnt[i] : 0;
    sm[threadIdx.x] = v;
    __syncthreads();
    for (int off = 1; off < SCAN_B; off <<= 1) {
        int u = (threadIdx.x >= off) ? sm[threadIdx.x - off] : 0;
        __syncthreads();
        sm[threadIdx.x] += u;
        __syncthreads();
    }
    if (i < Nn) {
        int b = bsum[blockIdx.x] + sm[threadIdx.x] - v;
        base[i] = b;
        cursor[i] = b;
    }
}

// ---------------------------------------------------------------------------
// XCD-bucketed CSR fill (kills scatter write amplification; see R5 notes)
// adjp[pos] = other | (side<<31)
// ---------------------------------------------------------------------------
__global__ __launch_bounds__(256) void fill_xcd(const int* __restrict__ idx,
                                                int* __restrict__ cursor,
                                                int* __restrict__ adjp,
                                                int E, int Nn)
{
    const int xcd  = blockIdx.x & 7;
    const int gblk = blockIdx.x >> 3;
    const int ngrp = gridDim.x >> 3;
    const int twoE = 2 * E;
    const int lo = xcd * Nn, hi = lo + Nn;   // bucket: lo <= 8*node < hi
    for (int i = gblk * blockDim.x + threadIdx.x; i < twoE; i += ngrp * blockDim.x) {
        int node = idx[i];
        int n8 = node << 3;
        if (n8 < lo || n8 >= hi) continue;
        int side  = (i >= E);
        int e     = side ? i - E : i;
        int other = side ? idx[e] : idx[E + e];
        int pos = atomicAdd(cursor + node, 1);
        adjp[pos] = other | (side << 31);
    }
}

// ===========================================================================
// per-step fused kernel: TWO nodes per wave (32-lane groups). A group's 32
// lanes cover one 256B half-row (8B/lane); prologue/epilogue amortize over
// 2 nodes. Wave-uniform while(__any) loop; masked groups carry alpha=0.
// ===========================================================================
template<bool LAST>
__global__ __launch_bounds__(256) void agg6(const f16* __restrict__ g16,
                                            const int* __restrict__ adjp,
                                            const int* __restrict__ base,
                                            const float* __restrict__ sIn,
                                            float* __restrict__ sOut,
                                            float* __restrict__ h,
                                            f16* __restrict__ h16,
                                            const float* __restrict__ wg,
                                            const float* __restrict__ gbp,
                                            const float* __restrict__ Tp,
                                            float stepf, int Nn, int twoE)
{
    const int lane = threadIdx.x & 63;
    const int grp  = lane >> 5;          // node slot within wave
    const int gl   = lane & 31;          // lane within group
    const int wvid = (blockIdx.x * blockDim.x + threadIdx.x) >> 6;
    int n = wvid * 2 + grp;
    const bool nOK = (n < Nn);
    if (n >= Nn) n = Nn - 1;             // clamp; writes guarded by nOK
    const float gb = gbp[0];
    const float w  = 1.f / (1.f + expf(-(Tp[0] - stepf)));
    const int b0 = base[n], b1 = base[n + 1];
    const int deg = b1 - b0;
    const float s1n = sIn[2 * n], s2n = sIn[2 * n + 1];
    const int d0 = gl << 2;              // f16 elem offset (4 elems = 8B/lane)

    // hoisted independent loads
    f16x4 o1 = *(const f16x4*)(g16 + (size_t)n * 256 + d0);
    f16x4 o2 = *(const f16x4*)(g16 + (size_t)n * 256 + 128 + d0);
    float4 hv = *(const float4*)(h + (size_t)n * DH + d0);

    f16x2 accLo = {(f16)0.f, (f16)0.f};
    f16x2 accHi = {(f16)0.f, (f16)0.f};
    float aPl = 0.f, aCl = 0.f;

    union V4 { f16x4 v; f16x2 h2[2]; };
    union AU { u32 w; f16x2 h; unsigned short us[2]; };

    int t = 0;
    while (__any(t * 32 < deg)) {
        const int done = t * 32;
        int m = deg - done; m = (m < 0) ? 0 : ((m > 32) ? 32 : m);
        int midx = b0 + done + ((gl < m) ? gl : ((m > 0) ? m - 1 : 0));
        midx = (midx < twoE - 1) ? midx : (twoE - 1);
        midx = (midx > 0) ? midx : 0;
        int meta  = adjp[midx];
        int other = meta & 0x7FFFFFFF;
        int side  = ((unsigned)meta) >> 31;
        int eoff  = (other << 8) | ((side ^ 1) << 7);   // f16 elem offset
        float sv  = sIn[2 * other + (side ^ 1)];
        float aE  = 1.f / (1.f + expf(-((side ? s2n : s1n) + sv + gb)));
        if (gl >= m) aE = 0.f;
        aPl += side ? 0.f : aE;
        aCl += side ? aE : 0.f;

        AU apk;
        apk.h[0] = (f16)aE;
        apk.us[1] = apk.us[0];

        const int sb = grp << 5;         // group's shfl base
        for (int j = 0; j < m; j += 8) {
            V4 gv[8]; u32 ap[8];
#pragma unroll
            for (int u = 0; u < 8; ++u) {
                int es = j + u; es = (es < 31) ? es : 31;
                int eo = __shfl(eoff, sb | es);
                ap[u]  = (u32)__shfl((int)apk.w, sb | es);
                gv[u].v = *(const f16x4*)(g16 + (size_t)(unsigned)eo + d0);
            }
#pragma unroll
            for (int u = 0; u < 8; ++u) {
                AU aa; aa.w = ap[u];
                accLo += aa.h * gv[u].h2[0];
                accHi += aa.h * gv[u].h2[1];
            }
        }
        ++t;
    }

    float ax = (float)accLo[0], ay = (float)accLo[1];
    float az = (float)accHi[0], aw = (float)accHi[1];

    // alpha totals by side (group-local butterflies)
    float aP = aPl, aC = aCl;
#pragma unroll
    for (int off = 16; off > 0; off >>= 1) {
        aP += __shfl_xor(aP, off);
        aC += __shfl_xor(aC, off);
    }
    // own-row contribution (f32)
    ax += aP * (float)o1[0] + aC * (float)o2[0];
    ay += aP * (float)o1[1] + aC * (float)o2[1];
    az += aP * (float)o1[2] + aC * (float)o2[2];
    aw += aP * (float)o1[3] + aC * (float)o2[3];

    hv.x += w * fmaxf(ax + hv.x, 0.f);
    hv.y += w * fmaxf(ay + hv.y, 0.f);
    hv.z += w * fmaxf(az + hv.z, 0.f);
    hv.w += w * fmaxf(aw + hv.w, 0.f);

    float p0 = 0.f, p1 = 0.f;
    if (nOK) {
        *(float4*)(h + (size_t)n * DH + d0) = hv;
        if constexpr (!LAST) {
            f16x4 h2 = {(f16)hv.x, (f16)hv.y, (f16)hv.z, (f16)hv.w};
            *(f16x4*)(h16 + (size_t)n * DH + d0) = h2;
        }
    }
    if constexpr (!LAST) {
        float4 w0 = *(const float4*)(wg + d0);
        float4 w1 = *(const float4*)(wg + 128 + d0);
        p0 = hv.x*w0.x + hv.y*w0.y + hv.z*w0.z + hv.w*w0.w;
        p1 = hv.x*w1.x + hv.y*w1.y + hv.z*w1.z + hv.w*w1.w;
#pragma unroll
        for (int off = 16; off > 0; off >>= 1) {
            p0 += __shfl_xor(p0, off);
            p1 += __shfl_xor(p1, off);
        }
        if (gl == 0 && nOK) *(float2*)(sOut + 2 * n) = make_float2(p0, p1);
    }
}

// ---------------------------------------------------------------------------
static inline size_t alignUp(size_t x) { return (x + 255) & ~(size_t)255; }

extern "C" void kernel_launch(void* const* d_in, const int* in_sizes, int n_in,
                              void* d_out, int out_size, void* d_ws, size_t ws_size,
                              hipStream_t stream)
{
    const float* x     = (const float*)d_in[0];
    const int*   idx   = (const int*)d_in[1];
    const float* Ws    = (const float*)d_in[2];
    const float* Wpc   = (const float*)d_in[3];
    const float* Wedge = (const float*)d_in[4];
    const float* Wg    = (const float*)d_in[5];
    const float* Wgb   = (const float*)d_in[6];
    const float* Tp    = (const float*)d_in[7];
    const int Nn = in_sizes[0] / DH;     // 100000
    const int E  = in_sizes[1] / 2;      // 500000
    float* h = (float*)d_out;

    const int nb = (Nn + SCAN_B - 1) / SCAN_B;
    if (nb > 1024) { fprintf(stderr, "kernel_launch: Nn too big for scan\n"); return; }

    // workspace carve-up
    size_t off = 0;
    char* wsb = (char*)d_ws;
    f16*   g16    = (f16*)  (wsb + off); off = alignUp(off + (size_t)Nn * 256 * 2);
    f16*   h16    = (f16*)  (wsb + off); off = alignUp(off + (size_t)Nn * DH * 2);
    f16*   x16    = (f16*)  (wsb + off); off = alignUp(off + (size_t)Nn * DH * 2);
    f16*   Ws16   = (f16*)  (wsb + off); off = alignUp(off + 128 * 128 * 2);
    f16*   Bg16   = (f16*)  (wsb + off); off = alignUp(off + 256 * 128 * 2);
    float* sA     = (float*)(wsb + off); off = alignUp(off + (size_t)Nn * 2 * 4);
    float* sB     = (float*)(wsb + off); off = alignUp(off + (size_t)Nn * 2 * 4);
    int*   cnt    = (int*)  (wsb + off); off = alignUp(off + (size_t)Nn * 4);
    int*   base   = (int*)  (wsb + off); off = alignUp(off + (size_t)(Nn + 1) * 4);
    int*   cursor = (int*)  (wsb + off); off = alignUp(off + (size_t)Nn * 4);
    int*   bsum   = (int*)  (wsb + off); off = alignUp(off + 1024 * 4);
    int*   adjp   = (int*)  (wsb + off); off = alignUp(off + (size_t)(2 * E + 64) * 4);
    if (off > ws_size) {
        fprintf(stderr, "kernel_launch: ws too small (%zu < %zu)\n", ws_size, off);
        return;
    }

    // ---- CSR build + input prep ----
    hipMemsetAsync(cnt, 0, (size_t)Nn * 4, stream);
    prep_k<<<dim3(2048), dim3(256), 0, stream>>>(idx, cnt, 2 * E, x, x16, Nn * DH / 4);
    scan1<<<dim3(nb), dim3(SCAN_B), 0, stream>>>(cnt, bsum, Nn);
    scan2<<<dim3(1), dim3(1024), 0, stream>>>(bsum, nb, base + Nn);
    scan3<<<dim3(nb), dim3(SCAN_B), 0, stream>>>(cnt, bsum, base, cursor, Nn);
    fill_xcd<<<dim3(1280), dim3(256), 0, stream>>>(idx, cursor, adjp, E, Nn);

    // ---- weights + init h (+ fused s) ----
    wc_kernel<<<dim3(384), dim3(128), 0, stream>>>(Wpc, Wedge, Ws, Bg16, Ws16);
    mfma_gemm_t<128, 2, true, true, true>
        <<<dim3((Nn + 127) / 128), dim3(256), 0, stream>>>(x16, Ws16, h, h16, Wg, sA, Nn);

    // ---- 3 steps ----
    const int aggBlocks = (Nn * 32 + 255) / 256;
    float* sCur = sA; float* sNxt = sB;
    for (int step = 0; step < 3; ++step) {
        mfma_gemm_t<256, 4, false, true, false>
            <<<dim3((Nn + 255) / 256), dim3(256), 0, stream>>>(h16, Bg16, nullptr, g16,
                                                               nullptr, nullptr, Nn);
        if (step < 2)
            agg6<false><<<dim3(aggBlocks), dim3(256), 0, stream>>>(g16, adjp, base, sCur,
                                                                   sNxt, h, h16, Wg, Wgb,
                                                                   Tp, (float)step, Nn, 2 * E);
        else
            agg6<true><<<dim3(aggBlocks), dim3(256), 0, stream>>>(g16, adjp, base, sCur,
                                                                  sNxt, h, h16, Wg, Wgb,
                                                                  Tp, (float)step, Nn, 2 * E);
        float* t = sCur; sCur = sNxt; sNxt = t;
    }
}